// Round 3
// baseline (372.489 us; speedup 1.0000x reference)
//
#include <hip/hip_runtime.h>
#include <hip/hip_fp16.h>

// GCN: N=100000, E=1600000, widths 128 -> 16 -> 64 -> 128 -> 1
// Round 14: (1) fuse head into gather64 (W3 in 32KB LDS, static readlane
// redistribution of the wave-held 64ch aggregate) -- kills aggS2 51MB
// round-trip + one dispatch; (2) pack bucketed edge records to 4B
// (src<<8 | dst&255) -- halves p2 write / p3 read; (3) SHIFT=8 buckets
// (391x391 count matrix, 4x smaller colscan, better p2 segment coalescing).
// Intermediates A/B/C fp16 storage, all math fp32 (R12). Zero global atomics
// CSR build (R13).
// Pipeline: count+gemm1 -> colscan -> basescan -> p2 -> p3
//           -> gather16(r1) -> g16gemm2(r2) -> gather64+head.

#define NN 100000
#define NE 1600000
#define SHIFT 8                      // 256 nodes per bucket
#define NB2 391                      // ceil(NN/256)
#define EPB 4096                     // edges per P1/P2 block
#define NBLK 391                     // ceil(NE/EPB)
#define CHUNK 7                      // ceil(NBLK/64) for colscan

__device__ __forceinline__ float rdl_f(float v, int l) {
    return __int_as_float(__builtin_amdgcn_readlane(__float_as_int(v), l));
}

// unpack one half2 word, accumulate into two fp32 lanes
__device__ __forceinline__ void h2acc(unsigned u, float& a, float& b) {
    __half2 h = *reinterpret_cast<__half2*>(&u);
    float2 f = __half22float2(h);
    a += f.x; b += f.y;
}
__device__ __forceinline__ unsigned packh2(float a, float b) {
    __half2 h = __floats2half2_rn(a, b);
    return *reinterpret_cast<unsigned*>(&h);
}
__device__ __forceinline__ unsigned sc2(unsigned u, float s) {
    __half2 h = *reinterpret_cast<__half2*>(&u);
    float2 f = __half22float2(h);
    return packh2(f.x * s, f.y * s);
}

// ---------------- P1: bucket counts (blocks < NBLK) + gemm1_raw (rest) ----------------
// gemm1_raw: A = x @ W1 (unscaled; dinv applied in P3), K=128, M=16, fp16 out.
__global__ __launch_bounds__(256) void count_gemm1_k(const int* __restrict__ dst,
                                                     int* __restrict__ mat,
                                                     const float* __restrict__ x,
                                                     const float* __restrict__ W1,
                                                     __half* __restrict__ A, int n) {
    __shared__ int cnt[NB2];
    __shared__ float sW[128 * 16];
    __shared__ float sIn[16][132];           // +4 pad
    const int tid = threadIdx.x;
    if ((int)blockIdx.x < NBLK) {
        for (int i = tid; i < NB2; i += 256) cnt[i] = 0;
        __syncthreads();
        const int e0 = blockIdx.x * EPB;
        const int e1 = min(e0 + EPB, NE);
        for (int i = e0 + tid; i < e1; i += 256) atomicAdd(&cnt[dst[i] >> SHIFT], 1);
        __syncthreads();
        for (int c = tid; c < NB2; c += 256) mat[blockIdx.x * NB2 + c] = cnt[c];
        return;
    }
    const int bid = blockIdx.x - NBLK;
    for (int i = tid; i < 128 * 16; i += 256) sW[i] = W1[i];
    const int row0 = bid * 16;
    const float4* in4 = (const float4*)x;
    for (int i = tid; i < 16 * 32; i += 256) {
        int r = i >> 5, kv = i & 31;
        int g = row0 + r;
        float4 v = make_float4(0.f, 0.f, 0.f, 0.f);
        if (g < n) v = in4[(long)g * 32 + kv];
        ((float4*)&sIn[r][0])[kv] = v;
    }
    __syncthreads();
    const int r = tid >> 4, m = tid & 15;
    const int g = row0 + r;
    if (g < n) {
        float acc = 0.0f;
#pragma unroll
        for (int k = 0; k < 128; ++k) acc += sIn[r][k] * sW[k * 16 + m];
        A[(long)g * 16 + m] = __float2half(acc);
    }
}

// ---------------- colscan: per-bucket exclusive scan over edge-blocks ----------------
// mat[b][c] (row-major) -> ofsT[b][c] = sum_{b'<b} mat[b'][c]; colTotal[c].
__global__ __launch_bounds__(64) void colscan_k(const int* __restrict__ mat,
                                                int* __restrict__ ofsT,
                                                int* __restrict__ colTotal) {
    const int c = blockIdx.x;
    const int lane = threadIdx.x;
    int v[CHUNK];
    int s = 0;
    const int base = lane * CHUNK;
#pragma unroll
    for (int j = 0; j < CHUNK; ++j) {
        int b = base + j;
        int x_ = (b < NBLK) ? mat[b * NB2 + c] : 0;
        v[j] = s;              // local exclusive prefix
        s += x_;
    }
    // wave exclusive scan of chunk sums
    int inc = s;
#pragma unroll
    for (int d = 1; d < 64; d <<= 1) {
        int t = __shfl_up(inc, d, 64);
        if (lane >= d) inc += t;
    }
    const int excl = inc - s;
#pragma unroll
    for (int j = 0; j < CHUNK; ++j) {
        int b = base + j;
        if (b < NBLK) ofsT[b * NB2 + c] = excl + v[j];
    }
    if (lane == 63) colTotal[c] = excl + s;
}

// ---------------- basescan: exclusive scan of bucket totals ----------------
__global__ __launch_bounds__(512) void basescan_k(const int* __restrict__ colTotal,
                                                  int* __restrict__ bucketBase,
                                                  int* __restrict__ rowptr) {
    __shared__ int s[512];
    const int t = threadIdx.x;
    int v = (t < NB2) ? colTotal[t] : 0;
    s[t] = v;
    __syncthreads();
    for (int off = 1; off < 512; off <<= 1) {
        int a = (t >= off) ? s[t - off] : 0;
        __syncthreads();
        s[t] += a;
        __syncthreads();
    }
    if (t < NB2) bucketBase[t] = s[t] - v;  // exclusive
    if (t == 0) { bucketBase[NB2] = NE; rowptr[NN] = NE; }
}

// ---------------- P2: scatter packed edges into bucket regions (LDS cursors) ----------
__global__ __launch_bounds__(256) void p2_scatter_k(const int* __restrict__ src,
                                                    const int* __restrict__ dst,
                                                    const int* __restrict__ ofsT,
                                                    const int* __restrict__ bucketBase,
                                                    unsigned* __restrict__ bucketed) {
    __shared__ int cur[NB2];
    const int b = blockIdx.x;
    const int tid = threadIdx.x;
    for (int c = tid; c < NB2; c += 256) cur[c] = bucketBase[c] + ofsT[b * NB2 + c];
    __syncthreads();
    const int e0 = b * EPB;
    const int e1 = min(e0 + EPB, NE);
    for (int i = e0 + tid; i < e1; i += 256) {
        const int d = dst[i];
        const int c = d >> SHIFT;
        const int pos = atomicAdd(&cur[c], 1);
        bucketed[pos] = ((unsigned)src[i] << 8) | (unsigned)(d & 255);
    }
}

// ---------------- P3: per-bucket CSR (rowptr, dinv, csr_src) + A rescale ----------------
__global__ __launch_bounds__(256) void p3_csr_k(const unsigned* __restrict__ bucketed,
                                                const int* __restrict__ bucketBase,
                                                int* __restrict__ rowptr,
                                                float* __restrict__ dinv,
                                                int* __restrict__ csr_src,
                                                __half* __restrict__ A) {
    __shared__ int cnt[256];
    __shared__ int excl[256];
    __shared__ float ld[256];
    const int c = blockIdx.x;
    const int tid = threadIdx.x;
    const int base = bucketBase[c];
    const int end = bucketBase[c + 1];
    cnt[tid] = 0;
    __syncthreads();
    // phase A: local histogram
    for (int i = base + tid; i < end; i += 256) atomicAdd(&cnt[bucketed[i] & 255u], 1);
    __syncthreads();
    // phase B: inclusive scan 256 (Hillis-Steele), write rowptr + dinv
    excl[tid] = cnt[tid];
    __syncthreads();
    for (int off = 1; off < 256; off <<= 1) {
        int a = (tid >= off) ? excl[tid - off] : 0;
        __syncthreads();
        excl[tid] += a;
        __syncthreads();
    }
    const int node0 = c << SHIFT;
    {
        const int node = node0 + tid;
        const int ex = excl[tid] - cnt[tid];
        if (node < NN) {
            rowptr[node] = base + ex;
            const float dv = rsqrtf((float)cnt[tid] + 1.0f);  // +1 self loop
            dinv[node] = dv;
            ld[tid] = dv;
        }
        excl[tid] = ex;  // becomes the fill cursor
    }
    __syncthreads();
    // phase C: scatter csr_src within this bucket's contiguous window
    for (int i = base + tid; i < end; i += 256) {
        const unsigned p = bucketed[i];
        const int pos = atomicAdd(&excl[p & 255u], 1);
        csr_src[base + pos] = (int)(p >> 8);
    }
    // phase D: rescale A row of this thread's node by dinv
    {
        const int node = node0 + tid;
        if (node < NN) {
            const float dv = ld[tid];
            uint4* p = (uint4*)(A + (long)node * 16);
            uint4 v0 = p[0], v1 = p[1];
            v0.x = sc2(v0.x, dv); v0.y = sc2(v0.y, dv);
            v0.z = sc2(v0.z, dv); v0.w = sc2(v0.w, dv);
            v1.x = sc2(v1.x, dv); v1.y = sc2(v1.y, dv);
            v1.z = sc2(v1.z, dv); v1.w = sc2(v1.w, dv);
            p[0] = v0; p[1] = v1;
        }
    }
}

// ---------------- pull-gather, 16 ch fp16: B = dinv*relu(dg*(sum A)+b1) ----------------
__global__ __launch_bounds__(256) void gather16h_k(const int* __restrict__ rowptr,
                                                   const int* __restrict__ csr_src,
                                                   const float* __restrict__ dinv,
                                                   const __half* __restrict__ hs,
                                                   const float* __restrict__ bias,
                                                   __half* __restrict__ outp, int n) {
    const int g = (blockIdx.x * 256 + threadIdx.x) >> 6;
    if (g >= n) return;
    const int lane = threadIdx.x & 63;
    const int q = lane & 3;                 // uint2 chunk within 16-ch row
    const int sub = lane >> 2;              // edge subgroup 0..15
    const float dg = dinv[g];
    const int beg = rowptr[g], end = rowptr[g + 1];
    const uint2* h2p = (const uint2*)hs;
    float a0 = 0.f, a1 = 0.f, a2 = 0.f, a3 = 0.f;
    if (sub == 0) {                          // self term
        uint2 v = h2p[(long)g * 4 + q];
        h2acc(v.x, a0, a1); h2acc(v.y, a2, a3);
    }
    for (int j0 = beg; j0 < end; j0 += 16) {
        int idx = j0 + sub;
        if (idx < end) {
            const int s = csr_src[idx];
            uint2 v = h2p[(long)s * 4 + q];
            h2acc(v.x, a0, a1); h2acc(v.y, a2, a3);
        }
    }
#pragma unroll
    for (int m = 4; m <= 32; m <<= 1) {
        a0 += __shfl_xor(a0, m, 64);
        a1 += __shfl_xor(a1, m, 64);
        a2 += __shfl_xor(a2, m, 64);
        a3 += __shfl_xor(a3, m, 64);
    }
    if (sub == 0) {
        const float4 b = ((const float4*)bias)[q];
        float v0 = fmaxf(fmaf(dg, a0, b.x), 0.0f) * dg;
        float v1 = fmaxf(fmaf(dg, a1, b.y), 0.0f) * dg;
        float v2 = fmaxf(fmaf(dg, a2, b.z), 0.0f) * dg;
        float v3 = fmaxf(fmaf(dg, a3, b.w), 0.0f) * dg;
        uint2 w;
        w.x = packh2(v0, v1);
        w.y = packh2(v2, v3);
        ((uint2*)outp)[(long)g * 4 + q] = w;
    }
}

// ---------------- fused gather16 + gemm2: C = dinv*relu(dg*(sum B)@W2 + b2), fp16 out ----
__global__ __launch_bounds__(256) void g16gemm2h_k(const int* __restrict__ rowptr,
                                                   const int* __restrict__ csr_src,
                                                   const float* __restrict__ dinv,
                                                   const __half* __restrict__ hs,
                                                   const float* __restrict__ W2,
                                                   const float* __restrict__ b2,
                                                   __half* __restrict__ outp, int n) {
    const int lane = threadIdx.x & 63;
    const int wid = blockIdx.x * 4 + (threadIdx.x >> 6);
    const int nWaves = gridDim.x * 4;
    float w2[16];
#pragma unroll
    for (int k = 0; k < 16; ++k) w2[k] = W2[k * 64 + lane];
    const float bm = b2[lane];
    const int q = lane & 3;
    const int sub = lane >> 2;
    const uint2* h2p = (const uint2*)hs;
    for (int g = wid; g < n; g += nWaves) {
        const float dg = dinv[g];
        const int beg = rowptr[g], end = rowptr[g + 1];
        float a0 = 0.f, a1 = 0.f, a2 = 0.f, a3 = 0.f;
        if (sub == 0) {                      // self term
            uint2 v = h2p[(long)g * 4 + q];
            h2acc(v.x, a0, a1); h2acc(v.y, a2, a3);
        }
        for (int j0 = beg; j0 < end; j0 += 16) {
            int idx = j0 + sub;
            if (idx < end) {
                const int s = csr_src[idx];
                uint2 v = h2p[(long)s * 4 + q];
                h2acc(v.x, a0, a1); h2acc(v.y, a2, a3);
            }
        }
#pragma unroll
        for (int m = 4; m <= 32; m <<= 1) {
            a0 += __shfl_xor(a0, m, 64);
            a1 += __shfl_xor(a1, m, 64);
            a2 += __shfl_xor(a2, m, 64);
            a3 += __shfl_xor(a3, m, 64);
        }
        float t = 0.0f;
#pragma unroll
        for (int ql = 0; ql < 4; ++ql) {
            t = fmaf(rdl_f(a0, ql), w2[4 * ql + 0], t);
            t = fmaf(rdl_f(a1, ql), w2[4 * ql + 1], t);
            t = fmaf(rdl_f(a2, ql), w2[4 * ql + 2], t);
            t = fmaf(rdl_f(a3, ql), w2[4 * ql + 3], t);
        }
        float r = fmaxf(fmaf(dg, t, bm), 0.0f);   // dg*(sum)@W2 + b2, relu
        outp[(long)g * 64 + lane] = __float2half(r * dg);  // pre-scaled fp16
    }
}

// ---------------- fused gather64 + head ----------------
// aggregation (8 lanes x uint4 per 128B fp16 row) then head math in-wave:
// agg channels live in a[0..7] replicated across sub-groups; x_k =
// readlane(a[k&7], k>>3) is a static-index redistribution. W3 staged in LDS.
__global__ __launch_bounds__(512) void gather64head_k(const int* __restrict__ rowptr,
                                                      const int* __restrict__ csr_src,
                                                      const float* __restrict__ dinv,
                                                      const __half* __restrict__ hs,
                                                      const float* __restrict__ W3,
                                                      const float* __restrict__ b3,
                                                      const float* __restrict__ Wfc,
                                                      const float* __restrict__ bfc,
                                                      float* __restrict__ out, int n) {
    __shared__ float sW3[64 * 128];          // 32 KB
    const int tid = threadIdx.x;
    for (int i = tid; i < 64 * 32; i += 512)
        ((float4*)sW3)[i] = ((const float4*)W3)[i];
    __syncthreads();
    const int lane = tid & 63;
    const int wid = blockIdx.x * 8 + (tid >> 6);
    const int nWaves = gridDim.x * 8;
    const int q = lane & 7;                 // uint4 chunk within 64-ch row
    const int sub = lane >> 3;              // edge subgroup 0..7
    const float bm0 = b3[lane], bm1 = b3[lane + 64];
    const float wf0 = Wfc[lane], wf1 = Wfc[lane + 64];
    const float bb = bfc[0];
    const uint4* h4 = (const uint4*)hs;     // row = 8 chunks of 16B
    for (int g = wid; g < n; g += nWaves) {
        const float dg = dinv[g];
        const int beg = rowptr[g], end = rowptr[g + 1];
        float a[8];
#pragma unroll
        for (int i = 0; i < 8; ++i) a[i] = 0.f;
        if (sub == 0) {                      // self term
            uint4 v = h4[(long)g * 8 + q];
            h2acc(v.x, a[0], a[1]); h2acc(v.y, a[2], a[3]);
            h2acc(v.z, a[4], a[5]); h2acc(v.w, a[6], a[7]);
        }
        int j0 = beg;
        for (; j0 + 16 <= end; j0 += 16) {
            const int s0 = csr_src[j0 + sub];
            const int s1 = csr_src[j0 + 8 + sub];
            const uint4 v0 = h4[(long)s0 * 8 + q];
            const uint4 v1 = h4[(long)s1 * 8 + q];
            h2acc(v0.x, a[0], a[1]); h2acc(v0.y, a[2], a[3]);
            h2acc(v0.z, a[4], a[5]); h2acc(v0.w, a[6], a[7]);
            h2acc(v1.x, a[0], a[1]); h2acc(v1.y, a[2], a[3]);
            h2acc(v1.z, a[4], a[5]); h2acc(v1.w, a[6], a[7]);
        }
        for (; j0 < end; j0 += 8) {
            int idx = j0 + sub;
            if (idx < end) {
                const int s = csr_src[idx];
                const uint4 v = h4[(long)s * 8 + q];
                h2acc(v.x, a[0], a[1]); h2acc(v.y, a[2], a[3]);
                h2acc(v.z, a[4], a[5]); h2acc(v.w, a[6], a[7]);
            }
        }
#pragma unroll
        for (int m = 8; m <= 32; m <<= 1) {
#pragma unroll
            for (int i = 0; i < 8; ++i) a[i] += __shfl_xor(a[i], m, 64);
        }
#pragma unroll
        for (int i = 0; i < 8; ++i) a[i] *= dg;   // aggS2 value, all lanes
        // head: each lane computes out-channels (lane, lane+64)
        float acc0 = 0.f, acc1 = 0.f;
#pragma unroll
        for (int k = 0; k < 64; ++k) {
            const float xk = rdl_f(a[k & 7], k >> 3);
            acc0 = fmaf(xk, sW3[k * 128 + lane], acc0);
            acc1 = fmaf(xk, sW3[k * 128 + 64 + lane], acc1);
        }
        float v = fmaxf(acc0 + bm0, 0.f) * wf0 + fmaxf(acc1 + bm1, 0.f) * wf1;
#pragma unroll
        for (int off = 32; off > 0; off >>= 1) v += __shfl_down(v, off, 64);
        if (lane == 0) out[g] = v + bb;
    }
}

extern "C" void kernel_launch(void* const* d_in, const int* in_sizes, int n_in,
                              void* d_out, int out_size, void* d_ws, size_t ws_size,
                              hipStream_t stream) {
    const float* x    = (const float*)d_in[0];
    const int*   ei   = (const int*)d_in[1];       // [2,E]: src = ei, dst = ei+E
    const float* W1   = (const float*)d_in[2];
    const float* b1   = (const float*)d_in[3];
    const float* W2   = (const float*)d_in[4];
    const float* b2   = (const float*)d_in[5];
    const float* W3   = (const float*)d_in[6];
    const float* b3   = (const float*)d_in[7];
    const float* Wfc  = (const float*)d_in[8];
    const float* bfc  = (const float*)d_in[9];
    float* out = (float*)d_out;

    const int* src = ei;
    const int* dst = ei + NE;

    // workspace layout (16B-aligned offsets; 4B units):
    // dinv[N] | rowptr[N+8] | mat[NBLK*NB2] | ofsT[NBLK*NB2] | colTotal[512]
    // | bucketBase[512] | csr_src[E+64] | bucketed[E] u32
    // | A_h[16N] fp16 | B_h[16N] fp16 | C_h[64N] fp16
    float* dinv        = (float*)d_ws;
    int*   rowptr      = (int*)(dinv + NN);
    int*   mat         = rowptr + NN + 8;
    int*   ofsT        = mat + NBLK * NB2 + 4;
    int*   colTotal    = ofsT + NBLK * NB2 + 4;
    int*   bucketBase  = colTotal + 512;
    int*   csr_src     = bucketBase + 512;
    unsigned* bucketed = (unsigned*)(csr_src + NE + 64);
    __half* A_h        = (__half*)(bucketed + NE);
    __half* B_h        = A_h + (long)NN * 16;
    __half* C_h        = B_h + (long)NN * 16;

    const int T = 256;

    // ---- CSR build (atomic-free) + gemm1_raw overlapped ----
    const int gemmBlocks = (NN + 15) / 16;             // 6250
    count_gemm1_k<<<NBLK + gemmBlocks, T, 0, stream>>>(dst, mat, x, W1, A_h, NN);
    colscan_k<<<NB2, 64, 0, stream>>>(mat, ofsT, colTotal);
    basescan_k<<<1, 512, 0, stream>>>(colTotal, bucketBase, rowptr);
    p2_scatter_k<<<NBLK, T, 0, stream>>>(src, dst, ofsT, bucketBase, bucketed);
    p3_csr_k<<<NB2, T, 0, stream>>>(bucketed, bucketBase, rowptr, dinv, csr_src, A_h);

    // ---- B = dinv * relu(dg*(sum A) + b1)  (pre-scaled r1, 16ch fp16) ----
    gather16h_k<<<(NN + 3) / 4, T, 0, stream>>>(rowptr, csr_src, dinv, A_h, b1, B_h, NN);
    // ---- C = dinv * relu(dg*(sum B)@W2 + b2)  (pre-scaled r2, 64ch fp16) ----
    g16gemm2h_k<<<3072, T, 0, stream>>>(rowptr, csr_src, dinv, B_h, W2, b2, C_h, NN);
    // ---- out = relu((dg*sum C)@W3 + b3).Wfc + bfc  (fused gather64 + head) ----
    gather64head_k<<<1024, 512, 0, stream>>>(rowptr, csr_src, dinv, C_h,
                                             W3, b3, Wfc, bfc, out, NN);
}

// Round 5
// 311.202 us; speedup vs baseline: 1.1969x; 1.1969x over previous
//
#include <hip/hip_runtime.h>
#include <hip/hip_fp16.h>

// GCN: N=100000, E=1600000, widths 128 -> 16 -> 64 -> 128 -> 1
// Round 16: RESUBMIT of R15 (bench died in harness infra: "Trio nursery"
// exception before any kernel verdict; source re-audited for barrier
// divergence / OOB -- none found).
// R15 contents: standalone 16-VGPR gather64h (occupancy-preserving, vs R14's
// fused version that collapsed to 21% occ); SHIFT=8 + 4B-packed bucketed;
// agg stored fp16 (-25.6MB HBM); basescan folded into p2/p3 via in-LDS
// rescan of colTotal; p3 sets rowptr[NN].
// Intermediates A/B/C/agg fp16 storage, all math fp32. Zero global atomics.
// Pipeline: count+gemm1 -> colscan -> p2 -> p3
//           -> gather16(r1) -> g16gemm2(r2) -> gather64 -> head.

#define NN 100000
#define NE 1600000
#define SHIFT 8                      // 256 nodes per bucket
#define NB2 391                      // ceil(NN/256)
#define EPB 4096                     // edges per P1/P2 block
#define NBLK 391                     // ceil(NE/EPB)
#define CHUNK 7                      // ceil(NBLK/64) for colscan

__device__ __forceinline__ float rdl_f(float v, int l) {
    return __int_as_float(__builtin_amdgcn_readlane(__float_as_int(v), l));
}

// unpack one half2 word, accumulate into two fp32 lanes
__device__ __forceinline__ void h2acc(unsigned u, float& a, float& b) {
    __half2 h = *reinterpret_cast<__half2*>(&u);
    float2 f = __half22float2(h);
    a += f.x; b += f.y;
}
__device__ __forceinline__ unsigned packh2(float a, float b) {
    __half2 h = __floats2half2_rn(a, b);
    return *reinterpret_cast<unsigned*>(&h);
}
__device__ __forceinline__ unsigned sc2(unsigned u, float s) {
    __half2 h = *reinterpret_cast<__half2*>(&u);
    float2 f = __half22float2(h);
    return packh2(f.x * s, f.y * s);
}

// ---------------- P1: bucket counts (blocks < NBLK) + gemm1_raw (rest) ----------------
// gemm1_raw: A = x @ W1 (unscaled; dinv applied in P3), K=128, M=16, fp16 out.
__global__ __launch_bounds__(256) void count_gemm1_k(const int* __restrict__ dst,
                                                     int* __restrict__ mat,
                                                     const float* __restrict__ x,
                                                     const float* __restrict__ W1,
                                                     __half* __restrict__ A, int n) {
    __shared__ int cnt[NB2];
    __shared__ float sW[128 * 16];
    __shared__ float sIn[16][132];           // +4 pad
    const int tid = threadIdx.x;
    if ((int)blockIdx.x < NBLK) {
        for (int i = tid; i < NB2; i += 256) cnt[i] = 0;
        __syncthreads();
        const int e0 = blockIdx.x * EPB;
        const int e1 = min(e0 + EPB, NE);
        for (int i = e0 + tid; i < e1; i += 256) atomicAdd(&cnt[dst[i] >> SHIFT], 1);
        __syncthreads();
        for (int c = tid; c < NB2; c += 256) mat[blockIdx.x * NB2 + c] = cnt[c];
        return;
    }
    const int bid = blockIdx.x - NBLK;
    for (int i = tid; i < 128 * 16; i += 256) sW[i] = W1[i];
    const int row0 = bid * 16;
    const float4* in4 = (const float4*)x;
    for (int i = tid; i < 16 * 32; i += 256) {
        int r = i >> 5, kv = i & 31;
        int g = row0 + r;
        float4 v = make_float4(0.f, 0.f, 0.f, 0.f);
        if (g < n) v = in4[(long)g * 32 + kv];
        ((float4*)&sIn[r][0])[kv] = v;
    }
    __syncthreads();
    const int r = tid >> 4, m = tid & 15;
    const int g = row0 + r;
    if (g < n) {
        float acc = 0.0f;
#pragma unroll
        for (int k = 0; k < 128; ++k) acc += sIn[r][k] * sW[k * 16 + m];
        A[(long)g * 16 + m] = __float2half(acc);
    }
}

// ---------------- colscan: per-bucket exclusive scan over edge-blocks ----------------
// mat[b][c] (row-major) -> ofsT[b][c] = sum_{b'<b} mat[b'][c]; colTotal[c].
__global__ __launch_bounds__(64) void colscan_k(const int* __restrict__ mat,
                                                int* __restrict__ ofsT,
                                                int* __restrict__ colTotal) {
    const int c = blockIdx.x;
    const int lane = threadIdx.x;
    int v[CHUNK];
    int s = 0;
    const int base = lane * CHUNK;
#pragma unroll
    for (int j = 0; j < CHUNK; ++j) {
        int b = base + j;
        int x_ = (b < NBLK) ? mat[b * NB2 + c] : 0;
        v[j] = s;              // local exclusive prefix
        s += x_;
    }
    // wave exclusive scan of chunk sums
    int inc = s;
#pragma unroll
    for (int d = 1; d < 64; d <<= 1) {
        int t = __shfl_up(inc, d, 64);
        if (lane >= d) inc += t;
    }
    const int excl = inc - s;
#pragma unroll
    for (int j = 0; j < CHUNK; ++j) {
        int b = base + j;
        if (b < NBLK) ofsT[b * NB2 + c] = excl + v[j];
    }
    if (lane == 63) colTotal[c] = excl + s;
}

// ---------------- P2: scatter packed edges into bucket regions ----------------
// bucketBase derived in-block from colTotal scan (no basescan dispatch).
__global__ __launch_bounds__(512) void p2_scatter_k(const int* __restrict__ src,
                                                    const int* __restrict__ dst,
                                                    const int* __restrict__ ofsT,
                                                    const int* __restrict__ colTotal,
                                                    unsigned* __restrict__ bucketed) {
    __shared__ int sc[512];
    __shared__ int cur[NB2];
    const int b = blockIdx.x;
    const int t = threadIdx.x;
    int v = (t < NB2) ? colTotal[t] : 0;
    sc[t] = v;
    __syncthreads();
    for (int off = 1; off < 512; off <<= 1) {
        int a = (t >= off) ? sc[t - off] : 0;
        __syncthreads();
        sc[t] += a;
        __syncthreads();
    }
    if (t < NB2) cur[t] = (sc[t] - v) + ofsT[b * NB2 + t];
    __syncthreads();
    const int e0 = b * EPB;
    const int e1 = min(e0 + EPB, NE);
    for (int i = e0 + t; i < e1; i += 512) {
        const int d = dst[i];
        const int c = d >> SHIFT;
        const int pos = atomicAdd(&cur[c], 1);
        bucketed[pos] = ((unsigned)src[i] << 8) | (unsigned)(d & 255);
    }
}

// ---------------- P3: per-bucket CSR (rowptr, dinv, csr_src) + A rescale ----------------
__global__ __launch_bounds__(512) void p3_csr_k(const unsigned* __restrict__ bucketed,
                                                const int* __restrict__ colTotal,
                                                int* __restrict__ rowptr,
                                                float* __restrict__ dinv,
                                                int* __restrict__ csr_src,
                                                __half* __restrict__ A) {
    __shared__ int sc[512];
    __shared__ int cnt[256];
    __shared__ int excl[256];
    __shared__ float ld[256];
    const int c = blockIdx.x;
    const int t = threadIdx.x;
    int v = (t < NB2) ? colTotal[t] : 0;
    sc[t] = v;
    if (t < 256) cnt[t] = 0;
    __syncthreads();
    for (int off = 1; off < 512; off <<= 1) {
        int a = (t >= off) ? sc[t - off] : 0;
        __syncthreads();
        sc[t] += a;
        __syncthreads();
    }
    const int end  = sc[c];
    const int base = (c > 0) ? sc[c - 1] : 0;
    // phase A: local histogram (cnt zeroed above; scan barriers ordered it)
    for (int i = base + t; i < end; i += 512) atomicAdd(&cnt[bucketed[i] & 255u], 1);
    __syncthreads();
    // phase B: inclusive scan of 256 counts with 512 threads (guarded)
    if (t < 256) excl[t] = cnt[t];
    __syncthreads();
    for (int off = 1; off < 256; off <<= 1) {
        int a = (t < 256 && t >= off) ? excl[t - off] : 0;
        __syncthreads();
        if (t < 256) excl[t] += a;
        __syncthreads();
    }
    const int node0 = c << SHIFT;
    if (t < 256) {
        const int node = node0 + t;
        const int ex = excl[t] - cnt[t];
        if (node < NN) {
            rowptr[node] = base + ex;
            const float dv = rsqrtf((float)cnt[t] + 1.0f);  // +1 self loop
            dinv[node] = dv;
            ld[t] = dv;
        }
        excl[t] = ex;  // becomes the fill cursor
    }
    if (c == NB2 - 1 && t == 0) rowptr[NN] = NE;
    __syncthreads();
    // phase C: scatter csr_src within this bucket's contiguous window
    for (int i = base + t; i < end; i += 512) {
        const unsigned p = bucketed[i];
        const int pos = atomicAdd(&excl[p & 255u], 1);
        csr_src[base + pos] = (int)(p >> 8);
    }
    // phase D: rescale A rows by dinv (2 threads per node)
    {
        const int node = node0 + (t >> 1);
        if (node < NN) {
            const float dv = ld[t >> 1];
            uint4* p = (uint4*)(A + (long)node * 16 + (t & 1) * 8);
            uint4 q = *p;
            q.x = sc2(q.x, dv); q.y = sc2(q.y, dv);
            q.z = sc2(q.z, dv); q.w = sc2(q.w, dv);
            *p = q;
        }
    }
}

// ---------------- pull-gather, 16 ch fp16: B = dinv*relu(dg*(sum A)+b1) ----------------
__global__ __launch_bounds__(256) void gather16h_k(const int* __restrict__ rowptr,
                                                   const int* __restrict__ csr_src,
                                                   const float* __restrict__ dinv,
                                                   const __half* __restrict__ hs,
                                                   const float* __restrict__ bias,
                                                   __half* __restrict__ outp, int n) {
    const int g = (blockIdx.x * 256 + threadIdx.x) >> 6;
    if (g >= n) return;
    const int lane = threadIdx.x & 63;
    const int q = lane & 3;                 // uint2 chunk within 16-ch row
    const int sub = lane >> 2;              // edge subgroup 0..15
    const float dg = dinv[g];
    const int beg = rowptr[g], end = rowptr[g + 1];
    const uint2* h2p = (const uint2*)hs;
    float a0 = 0.f, a1 = 0.f, a2 = 0.f, a3 = 0.f;
    if (sub == 0) {                          // self term
        uint2 v = h2p[(long)g * 4 + q];
        h2acc(v.x, a0, a1); h2acc(v.y, a2, a3);
    }
    for (int j0 = beg; j0 < end; j0 += 16) {
        int idx = j0 + sub;
        if (idx < end) {
            const int s = csr_src[idx];
            uint2 v = h2p[(long)s * 4 + q];
            h2acc(v.x, a0, a1); h2acc(v.y, a2, a3);
        }
    }
#pragma unroll
    for (int m = 4; m <= 32; m <<= 1) {
        a0 += __shfl_xor(a0, m, 64);
        a1 += __shfl_xor(a1, m, 64);
        a2 += __shfl_xor(a2, m, 64);
        a3 += __shfl_xor(a3, m, 64);
    }
    if (sub == 0) {
        const float4 b = ((const float4*)bias)[q];
        float v0 = fmaxf(fmaf(dg, a0, b.x), 0.0f) * dg;
        float v1 = fmaxf(fmaf(dg, a1, b.y), 0.0f) * dg;
        float v2 = fmaxf(fmaf(dg, a2, b.z), 0.0f) * dg;
        float v3 = fmaxf(fmaf(dg, a3, b.w), 0.0f) * dg;
        uint2 w;
        w.x = packh2(v0, v1);
        w.y = packh2(v2, v3);
        ((uint2*)outp)[(long)g * 4 + q] = w;
    }
}

// ---------------- fused gather16 + gemm2: C = dinv*relu(dg*(sum B)@W2 + b2), fp16 out ----
__global__ __launch_bounds__(256) void g16gemm2h_k(const int* __restrict__ rowptr,
                                                   const int* __restrict__ csr_src,
                                                   const float* __restrict__ dinv,
                                                   const __half* __restrict__ hs,
                                                   const float* __restrict__ W2,
                                                   const float* __restrict__ b2,
                                                   __half* __restrict__ outp, int n) {
    const int lane = threadIdx.x & 63;
    const int wid = blockIdx.x * 4 + (threadIdx.x >> 6);
    const int nWaves = gridDim.x * 4;
    float w2[16];
#pragma unroll
    for (int k = 0; k < 16; ++k) w2[k] = W2[k * 64 + lane];
    const float bm = b2[lane];
    const int q = lane & 3;
    const int sub = lane >> 2;
    const uint2* h2p = (const uint2*)hs;
    for (int g = wid; g < n; g += nWaves) {
        const float dg = dinv[g];
        const int beg = rowptr[g], end = rowptr[g + 1];
        float a0 = 0.f, a1 = 0.f, a2 = 0.f, a3 = 0.f;
        if (sub == 0) {                      // self term
            uint2 v = h2p[(long)g * 4 + q];
            h2acc(v.x, a0, a1); h2acc(v.y, a2, a3);
        }
        for (int j0 = beg; j0 < end; j0 += 16) {
            int idx = j0 + sub;
            if (idx < end) {
                const int s = csr_src[idx];
                uint2 v = h2p[(long)s * 4 + q];
                h2acc(v.x, a0, a1); h2acc(v.y, a2, a3);
            }
        }
#pragma unroll
        for (int m = 4; m <= 32; m <<= 1) {
            a0 += __shfl_xor(a0, m, 64);
            a1 += __shfl_xor(a1, m, 64);
            a2 += __shfl_xor(a2, m, 64);
            a3 += __shfl_xor(a3, m, 64);
        }
        float t = 0.0f;
#pragma unroll
        for (int ql = 0; ql < 4; ++ql) {
            t = fmaf(rdl_f(a0, ql), w2[4 * ql + 0], t);
            t = fmaf(rdl_f(a1, ql), w2[4 * ql + 1], t);
            t = fmaf(rdl_f(a2, ql), w2[4 * ql + 2], t);
            t = fmaf(rdl_f(a3, ql), w2[4 * ql + 3], t);
        }
        float r = fmaxf(fmaf(dg, t, bm), 0.0f);   // dg*(sum)@W2 + b2, relu
        outp[(long)g * 64 + lane] = __float2half(r * dg);  // pre-scaled fp16
    }
}

// ---------------- pull-gather, 64 ch fp16: agg = dg * sum C  (fp16 out) ----------------
// 8 lanes x uint4 (16B) per 128B row (exactly one cache line per edge).
__global__ __launch_bounds__(256) void gather64h_k(const int* __restrict__ rowptr,
                                                   const int* __restrict__ csr_src,
                                                   const float* __restrict__ dinv,
                                                   const __half* __restrict__ hs,
                                                   __half* __restrict__ outp, int n) {
    const int g = (blockIdx.x * 256 + threadIdx.x) >> 6;
    if (g >= n) return;
    const int lane = threadIdx.x & 63;
    const int q = lane & 7;                 // uint4 chunk within 64-ch row
    const int sub = lane >> 3;              // edge subgroup 0..7
    const float dg = dinv[g];
    const int beg = rowptr[g], end = rowptr[g + 1];
    const uint4* h4 = (const uint4*)hs;     // row = 8 chunks of 16B
    float a[8];
#pragma unroll
    for (int i = 0; i < 8; ++i) a[i] = 0.f;
    if (sub == 0) {                          // self term
        uint4 v = h4[(long)g * 8 + q];
        h2acc(v.x, a[0], a[1]); h2acc(v.y, a[2], a[3]);
        h2acc(v.z, a[4], a[5]); h2acc(v.w, a[6], a[7]);
    }
    int j0 = beg;
    for (; j0 + 16 <= end; j0 += 16) {
        const int s0 = csr_src[j0 + sub];
        const int s1 = csr_src[j0 + 8 + sub];
        const uint4 v0 = h4[(long)s0 * 8 + q];
        const uint4 v1 = h4[(long)s1 * 8 + q];
        h2acc(v0.x, a[0], a[1]); h2acc(v0.y, a[2], a[3]);
        h2acc(v0.z, a[4], a[5]); h2acc(v0.w, a[6], a[7]);
        h2acc(v1.x, a[0], a[1]); h2acc(v1.y, a[2], a[3]);
        h2acc(v1.z, a[4], a[5]); h2acc(v1.w, a[6], a[7]);
    }
    for (; j0 < end; j0 += 8) {
        int idx = j0 + sub;
        if (idx < end) {
            const int s = csr_src[idx];
            const uint4 v = h4[(long)s * 8 + q];
            h2acc(v.x, a[0], a[1]); h2acc(v.y, a[2], a[3]);
            h2acc(v.z, a[4], a[5]); h2acc(v.w, a[6], a[7]);
        }
    }
#pragma unroll
    for (int m = 8; m <= 32; m <<= 1) {
#pragma unroll
        for (int i = 0; i < 8; ++i) a[i] += __shfl_xor(a[i], m, 64);
    }
    if (sub == 0) {
        uint4 w;
        w.x = packh2(a[0] * dg, a[1] * dg);
        w.y = packh2(a[2] * dg, a[3] * dg);
        w.z = packh2(a[4] * dg, a[5] * dg);
        w.w = packh2(a[6] * dg, a[7] * dg);
        ((uint4*)outp)[(long)g * 8 + q] = w;
    }
}

// ---------------- zero-LDS head: W3 in VGPRs, readlane broadcast (fp16 agg in) --------
__global__ __launch_bounds__(256) void head_k(const __half* __restrict__ agg,
                                              const float* __restrict__ W3,
                                              const float* __restrict__ b3,
                                              const float* __restrict__ Wfc,
                                              const float* __restrict__ bfc,
                                              float* __restrict__ out, int n) {
    const int lane = threadIdx.x & 63;
    const int wid = blockIdx.x * 4 + (threadIdx.x >> 6);
    const int nWaves = gridDim.x * 4;
    float w0[64], w1[64];
#pragma unroll
    for (int k = 0; k < 64; ++k) {
        w0[k] = W3[k * 128 + lane];
        w1[k] = W3[k * 128 + lane + 64];
    }
    const float bm0 = b3[lane], bm1 = b3[lane + 64];
    const float wf0 = Wfc[lane], wf1 = Wfc[lane + 64];
    const float bb = bfc[0];
    for (int g0 = wid * 4; g0 < n; g0 += nWaves * 4) {
        const __half* base = agg + (long)g0 * 64 + lane;
        const float rv0 = __half2float(base[0]);
        const float rv1 = __half2float(base[64]);
        const float rv2 = __half2float(base[128]);
        const float rv3 = __half2float(base[192]);
        float a00 = 0.f, a01 = 0.f, a10 = 0.f, a11 = 0.f;
        float a20 = 0.f, a21 = 0.f, a30 = 0.f, a31 = 0.f;
#pragma unroll
        for (int k = 0; k < 64; ++k) {
            const float x0 = rdl_f(rv0, k);
            const float x1 = rdl_f(rv1, k);
            const float x2 = rdl_f(rv2, k);
            const float x3 = rdl_f(rv3, k);
            a00 = fmaf(x0, w0[k], a00); a01 = fmaf(x0, w1[k], a01);
            a10 = fmaf(x1, w0[k], a10); a11 = fmaf(x1, w1[k], a11);
            a20 = fmaf(x2, w0[k], a20); a21 = fmaf(x2, w1[k], a21);
            a30 = fmaf(x3, w0[k], a30); a31 = fmaf(x3, w1[k], a31);
        }
        float v0 = fmaxf(a00 + bm0, 0.f) * wf0 + fmaxf(a01 + bm1, 0.f) * wf1;
        float v1 = fmaxf(a10 + bm0, 0.f) * wf0 + fmaxf(a11 + bm1, 0.f) * wf1;
        float v2 = fmaxf(a20 + bm0, 0.f) * wf0 + fmaxf(a21 + bm1, 0.f) * wf1;
        float v3 = fmaxf(a30 + bm0, 0.f) * wf0 + fmaxf(a31 + bm1, 0.f) * wf1;
#pragma unroll
        for (int off = 32; off > 0; off >>= 1) {
            v0 += __shfl_down(v0, off, 64);
            v1 += __shfl_down(v1, off, 64);
            v2 += __shfl_down(v2, off, 64);
            v3 += __shfl_down(v3, off, 64);
        }
        if (lane == 0)
            ((float4*)out)[g0 >> 2] = make_float4(v0 + bb, v1 + bb, v2 + bb, v3 + bb);
    }
}

extern "C" void kernel_launch(void* const* d_in, const int* in_sizes, int n_in,
                              void* d_out, int out_size, void* d_ws, size_t ws_size,
                              hipStream_t stream) {
    const float* x    = (const float*)d_in[0];
    const int*   ei   = (const int*)d_in[1];       // [2,E]: src = ei, dst = ei+E
    const float* W1   = (const float*)d_in[2];
    const float* b1   = (const float*)d_in[3];
    const float* W2   = (const float*)d_in[4];
    const float* b2   = (const float*)d_in[5];
    const float* W3   = (const float*)d_in[6];
    const float* b3   = (const float*)d_in[7];
    const float* Wfc  = (const float*)d_in[8];
    const float* bfc  = (const float*)d_in[9];
    float* out = (float*)d_out;

    const int* src = ei;
    const int* dst = ei + NE;

    // workspace layout (16B-aligned offsets; 4B units):
    // dinv[N] | rowptr[N+8] | mat[NBLK*NB2] | ofsT[NBLK*NB2] | colTotal[512]
    // | csr_src[E+64] | bucketed[E] u32
    // | A_h[16N] fp16 | B_h[16N] fp16 | C_h[64N] fp16 | agg_h[64N] fp16
    float* dinv        = (float*)d_ws;
    int*   rowptr      = (int*)(dinv + NN);
    int*   mat         = rowptr + NN + 8;
    int*   ofsT        = mat + NBLK * NB2 + 4;
    int*   colTotal    = ofsT + NBLK * NB2 + 4;
    int*   csr_src     = colTotal + 512;
    unsigned* bucketed = (unsigned*)(csr_src + NE + 64);
    __half* A_h        = (__half*)(bucketed + NE);
    __half* B_h        = A_h + (long)NN * 16;
    __half* C_h        = B_h + (long)NN * 16;
    __half* agg_h      = C_h + (long)NN * 64;

    const int T = 256;

    // ---- CSR build (atomic-free) + gemm1_raw overlapped ----
    const int gemmBlocks = (NN + 15) / 16;             // 6250
    count_gemm1_k<<<NBLK + gemmBlocks, T, 0, stream>>>(dst, mat, x, W1, A_h, NN);
    colscan_k<<<NB2, 64, 0, stream>>>(mat, ofsT, colTotal);
    p2_scatter_k<<<NBLK, 512, 0, stream>>>(src, dst, ofsT, colTotal, bucketed);
    p3_csr_k<<<NB2, 512, 0, stream>>>(bucketed, colTotal, rowptr, dinv, csr_src, A_h);

    // ---- B = dinv * relu(dg*(sum A) + b1)  (pre-scaled r1, 16ch fp16) ----
    gather16h_k<<<(NN + 3) / 4, T, 0, stream>>>(rowptr, csr_src, dinv, A_h, b1, B_h, NN);
    // ---- C = dinv * relu(dg*(sum B)@W2 + b2)  (pre-scaled r2, 64ch fp16) ----
    g16gemm2h_k<<<3072, T, 0, stream>>>(rowptr, csr_src, dinv, B_h, W2, b2, C_h, NN);
    // ---- agg(64ch fp16) = dg * sum C ----
    gather64h_k<<<(NN + 3) / 4, T, 0, stream>>>(rowptr, csr_src, dinv, C_h, agg_h, NN);
    // ---- head: out = relu(agg@W3 + b3).Wfc + bfc ----
    head_k<<<2048, T, 0, stream>>>(agg_h, W3, b3, Wfc, bfc, out, NN);
}

// Round 6
// 276.777 us; speedup vs baseline: 1.3458x; 1.1244x over previous
//
#include <hip/hip_runtime.h>
#include <hip/hip_fp16.h>

// GCN: N=100000, E=1600000, widths 128 -> 16 -> 64 -> 128 -> 1
// Round 17 (from 311.2us R16 baseline):
//  (1) gemm1 inner loop: x-tile + W1 staged as half2 (fp32 accum) -> LDS
//      reads per MAC halved (was 2x f32; ~21us of LDS issue -> ~10).
//  (2) head_k -> MFMA: agg fp16 @ W3-as-fp16, mfma_f32_16x16x32_f16, W3
//      staged in LDS in frag layout (conflict-free ds_read_b128), fused
//      relu+Wfc reduce in-wave. VALU-issue 15us -> ~6us.
//  (3) gather64h: persistent grid + unroll-4 (4 indep load chains);
//      gather16h: persistent grid. Removes 25k-block launch overhead.
// absmax note: bit-identical 3.051758e-05 across ALL fp16 storage changes
// (R11..R16) -> error floor is elsewhere; fp16 W3/x-input safe.
// Pipeline: count+gemm1 -> colscan -> p2 -> p3
//           -> gather16(r1) -> g16gemm2(r2) -> gather64 -> head(MFMA).

#define NN 100000
#define NE 1600000
#define SHIFT 8                      // 256 nodes per bucket
#define NB2 391                      // ceil(NN/256)
#define EPB 4096                     // edges per P1/P2 block
#define NBLK 391                     // ceil(NE/EPB)
#define CHUNK 7                      // ceil(NBLK/64) for colscan

typedef _Float16 half8 __attribute__((ext_vector_type(8)));
typedef float f32x4 __attribute__((ext_vector_type(4)));

__device__ __forceinline__ float rdl_f(float v, int l) {
    return __int_as_float(__builtin_amdgcn_readlane(__float_as_int(v), l));
}

// unpack one half2 word, accumulate into two fp32 lanes
__device__ __forceinline__ void h2acc(unsigned u, float& a, float& b) {
    __half2 h = *reinterpret_cast<__half2*>(&u);
    float2 f = __half22float2(h);
    a += f.x; b += f.y;
}
__device__ __forceinline__ unsigned packh2(float a, float b) {
    __half2 h = __floats2half2_rn(a, b);
    return *reinterpret_cast<unsigned*>(&h);
}
__device__ __forceinline__ unsigned sc2(unsigned u, float s) {
    __half2 h = *reinterpret_cast<__half2*>(&u);
    float2 f = __half22float2(h);
    return packh2(f.x * s, f.y * s);
}

// ---------------- P1: bucket counts (blocks < NBLK) + gemm1_raw (rest) ----------------
// gemm1_raw: A = x @ W1 (unscaled; dinv applied in P3), K=128, M=16, fp16 out.
// half2-staged LDS: 1 LDS read per 2 MACs on each operand.
__global__ __launch_bounds__(256) void count_gemm1_k(const int* __restrict__ dst,
                                                     int* __restrict__ mat,
                                                     const float* __restrict__ x,
                                                     const float* __restrict__ W1,
                                                     __half* __restrict__ A, int n) {
    __shared__ int cnt[NB2];
    __shared__ unsigned sW2[64 * 16];        // half2[k2][m]
    __shared__ unsigned sIn2[16][66];        // half2 row chunks, +2 pad
    const int tid = threadIdx.x;
    if ((int)blockIdx.x < NBLK) {
        for (int i = tid; i < NB2; i += 256) cnt[i] = 0;
        __syncthreads();
        const int e0 = blockIdx.x * EPB;
        const int e1 = min(e0 + EPB, NE);
        for (int i = e0 + tid; i < e1; i += 256) atomicAdd(&cnt[dst[i] >> SHIFT], 1);
        __syncthreads();
        for (int c = tid; c < NB2; c += 256) mat[blockIdx.x * NB2 + c] = cnt[c];
        return;
    }
    const int bid = blockIdx.x - NBLK;
    for (int i = tid; i < 64 * 16; i += 256) {
        const int k2 = i >> 4, m = i & 15;
        sW2[i] = packh2(W1[(2 * k2) * 16 + m], W1[(2 * k2 + 1) * 16 + m]);
    }
    const int row0 = bid * 16;
    const float4* in4 = (const float4*)x;
    for (int i = tid; i < 16 * 32; i += 256) {
        int r = i >> 5, kv = i & 31;
        int g = row0 + r;
        float4 v = make_float4(0.f, 0.f, 0.f, 0.f);
        if (g < n) v = in4[(long)g * 32 + kv];
        sIn2[r][kv * 2]     = packh2(v.x, v.y);
        sIn2[r][kv * 2 + 1] = packh2(v.z, v.w);
    }
    __syncthreads();
    const int r = tid >> 4, m = tid & 15;
    const int g = row0 + r;
    if (g < n) {
        float acc = 0.0f;
#pragma unroll
        for (int k2 = 0; k2 < 64; ++k2) {
            const __half2 a = *reinterpret_cast<const __half2*>(&sIn2[r][k2]);
            const __half2 w = *reinterpret_cast<const __half2*>(&sW2[k2 * 16 + m]);
            const float2 af = __half22float2(a);
            const float2 wf = __half22float2(w);
            acc = fmaf(af.x, wf.x, acc);
            acc = fmaf(af.y, wf.y, acc);
        }
        A[(long)g * 16 + m] = __float2half(acc);
    }
}

// ---------------- colscan: per-bucket exclusive scan over edge-blocks ----------------
__global__ __launch_bounds__(64) void colscan_k(const int* __restrict__ mat,
                                                int* __restrict__ ofsT,
                                                int* __restrict__ colTotal) {
    const int c = blockIdx.x;
    const int lane = threadIdx.x;
    int v[CHUNK];
    int s = 0;
    const int base = lane * CHUNK;
#pragma unroll
    for (int j = 0; j < CHUNK; ++j) {
        int b = base + j;
        int x_ = (b < NBLK) ? mat[b * NB2 + c] : 0;
        v[j] = s;              // local exclusive prefix
        s += x_;
    }
    int inc = s;
#pragma unroll
    for (int d = 1; d < 64; d <<= 1) {
        int t = __shfl_up(inc, d, 64);
        if (lane >= d) inc += t;
    }
    const int excl = inc - s;
#pragma unroll
    for (int j = 0; j < CHUNK; ++j) {
        int b = base + j;
        if (b < NBLK) ofsT[b * NB2 + c] = excl + v[j];
    }
    if (lane == 63) colTotal[c] = excl + s;
}

// ---------------- P2: scatter packed edges into bucket regions ----------------
__global__ __launch_bounds__(512) void p2_scatter_k(const int* __restrict__ src,
                                                    const int* __restrict__ dst,
                                                    const int* __restrict__ ofsT,
                                                    const int* __restrict__ colTotal,
                                                    unsigned* __restrict__ bucketed) {
    __shared__ int sc[512];
    __shared__ int cur[NB2];
    const int b = blockIdx.x;
    const int t = threadIdx.x;
    int v = (t < NB2) ? colTotal[t] : 0;
    sc[t] = v;
    __syncthreads();
    for (int off = 1; off < 512; off <<= 1) {
        int a = (t >= off) ? sc[t - off] : 0;
        __syncthreads();
        sc[t] += a;
        __syncthreads();
    }
    if (t < NB2) cur[t] = (sc[t] - v) + ofsT[b * NB2 + t];
    __syncthreads();
    const int e0 = b * EPB;
    const int e1 = min(e0 + EPB, NE);
    for (int i = e0 + t; i < e1; i += 512) {
        const int d = dst[i];
        const int c = d >> SHIFT;
        const int pos = atomicAdd(&cur[c], 1);
        bucketed[pos] = ((unsigned)src[i] << 8) | (unsigned)(d & 255);
    }
}

// ---------------- P3: per-bucket CSR (rowptr, dinv, csr_src) + A rescale ----------------
__global__ __launch_bounds__(512) void p3_csr_k(const unsigned* __restrict__ bucketed,
                                                const int* __restrict__ colTotal,
                                                int* __restrict__ rowptr,
                                                float* __restrict__ dinv,
                                                int* __restrict__ csr_src,
                                                __half* __restrict__ A) {
    __shared__ int sc[512];
    __shared__ int cnt[256];
    __shared__ int excl[256];
    __shared__ float ld[256];
    const int c = blockIdx.x;
    const int t = threadIdx.x;
    int v = (t < NB2) ? colTotal[t] : 0;
    sc[t] = v;
    if (t < 256) cnt[t] = 0;
    __syncthreads();
    for (int off = 1; off < 512; off <<= 1) {
        int a = (t >= off) ? sc[t - off] : 0;
        __syncthreads();
        sc[t] += a;
        __syncthreads();
    }
    const int end  = sc[c];
    const int base = (c > 0) ? sc[c - 1] : 0;
    for (int i = base + t; i < end; i += 512) atomicAdd(&cnt[bucketed[i] & 255u], 1);
    __syncthreads();
    if (t < 256) excl[t] = cnt[t];
    __syncthreads();
    for (int off = 1; off < 256; off <<= 1) {
        int a = (t < 256 && t >= off) ? excl[t - off] : 0;
        __syncthreads();
        if (t < 256) excl[t] += a;
        __syncthreads();
    }
    const int node0 = c << SHIFT;
    if (t < 256) {
        const int node = node0 + t;
        const int ex = excl[t] - cnt[t];
        if (node < NN) {
            rowptr[node] = base + ex;
            const float dv = rsqrtf((float)cnt[t] + 1.0f);  // +1 self loop
            dinv[node] = dv;
            ld[t] = dv;
        }
        excl[t] = ex;  // becomes the fill cursor
    }
    if (c == NB2 - 1 && t == 0) rowptr[NN] = NE;
    __syncthreads();
    for (int i = base + t; i < end; i += 512) {
        const unsigned p = bucketed[i];
        const int pos = atomicAdd(&excl[p & 255u], 1);
        csr_src[base + pos] = (int)(p >> 8);
    }
    {
        const int node = node0 + (t >> 1);
        if (node < NN) {
            const float dv = ld[t >> 1];
            uint4* p = (uint4*)(A + (long)node * 16 + (t & 1) * 8);
            uint4 q = *p;
            q.x = sc2(q.x, dv); q.y = sc2(q.y, dv);
            q.z = sc2(q.z, dv); q.w = sc2(q.w, dv);
            *p = q;
        }
    }
}

// ---------------- pull-gather, 16 ch fp16 (persistent): B = dinv*relu(dg*(sum A)+b1) ----
__global__ __launch_bounds__(256) void gather16h_k(const int* __restrict__ rowptr,
                                                   const int* __restrict__ csr_src,
                                                   const float* __restrict__ dinv,
                                                   const __half* __restrict__ hs,
                                                   const float* __restrict__ bias,
                                                   __half* __restrict__ outp, int n) {
    const int lane = threadIdx.x & 63;
    const int wid0 = blockIdx.x * 4 + (threadIdx.x >> 6);
    const int nWaves = gridDim.x * 4;
    const int q = lane & 3;                 // uint2 chunk within 16-ch row
    const int sub = lane >> 2;              // edge subgroup 0..15
    const uint2* h2p = (const uint2*)hs;
    const float4 b = ((const float4*)bias)[q];
    for (int g = wid0; g < n; g += nWaves) {
        const float dg = dinv[g];
        const int beg = rowptr[g], end = rowptr[g + 1];
        float a0 = 0.f, a1 = 0.f, a2 = 0.f, a3 = 0.f;
        if (sub == 0) {                      // self term
            uint2 v = h2p[(long)g * 4 + q];
            h2acc(v.x, a0, a1); h2acc(v.y, a2, a3);
        }
        for (int j0 = beg; j0 < end; j0 += 16) {
            int idx = j0 + sub;
            if (idx < end) {
                const int s = csr_src[idx];
                uint2 v = h2p[(long)s * 4 + q];
                h2acc(v.x, a0, a1); h2acc(v.y, a2, a3);
            }
        }
#pragma unroll
        for (int m = 4; m <= 32; m <<= 1) {
            a0 += __shfl_xor(a0, m, 64);
            a1 += __shfl_xor(a1, m, 64);
            a2 += __shfl_xor(a2, m, 64);
            a3 += __shfl_xor(a3, m, 64);
        }
        if (sub == 0) {
            float v0 = fmaxf(fmaf(dg, a0, b.x), 0.0f) * dg;
            float v1 = fmaxf(fmaf(dg, a1, b.y), 0.0f) * dg;
            float v2 = fmaxf(fmaf(dg, a2, b.z), 0.0f) * dg;
            float v3 = fmaxf(fmaf(dg, a3, b.w), 0.0f) * dg;
            uint2 w;
            w.x = packh2(v0, v1);
            w.y = packh2(v2, v3);
            ((uint2*)outp)[(long)g * 4 + q] = w;
        }
    }
}

// ---------------- fused gather16 + gemm2: C = dinv*relu(dg*(sum B)@W2 + b2), fp16 out ----
__global__ __launch_bounds__(256) void g16gemm2h_k(const int* __restrict__ rowptr,
                                                   const int* __restrict__ csr_src,
                                                   const float* __restrict__ dinv,
                                                   const __half* __restrict__ hs,
                                                   const float* __restrict__ W2,
                                                   const float* __restrict__ b2,
                                                   __half* __restrict__ outp, int n) {
    const int lane = threadIdx.x & 63;
    const int wid = blockIdx.x * 4 + (threadIdx.x >> 6);
    const int nWaves = gridDim.x * 4;
    float w2[16];
#pragma unroll
    for (int k = 0; k < 16; ++k) w2[k] = W2[k * 64 + lane];
    const float bm = b2[lane];
    const int q = lane & 3;
    const int sub = lane >> 2;
    const uint2* h2p = (const uint2*)hs;
    for (int g = wid; g < n; g += nWaves) {
        const float dg = dinv[g];
        const int beg = rowptr[g], end = rowptr[g + 1];
        float a0 = 0.f, a1 = 0.f, a2 = 0.f, a3 = 0.f;
        if (sub == 0) {                      // self term
            uint2 v = h2p[(long)g * 4 + q];
            h2acc(v.x, a0, a1); h2acc(v.y, a2, a3);
        }
        for (int j0 = beg; j0 < end; j0 += 16) {
            int idx = j0 + sub;
            if (idx < end) {
                const int s = csr_src[idx];
                uint2 v = h2p[(long)s * 4 + q];
                h2acc(v.x, a0, a1); h2acc(v.y, a2, a3);
            }
        }
#pragma unroll
        for (int m = 4; m <= 32; m <<= 1) {
            a0 += __shfl_xor(a0, m, 64);
            a1 += __shfl_xor(a1, m, 64);
            a2 += __shfl_xor(a2, m, 64);
            a3 += __shfl_xor(a3, m, 64);
        }
        float t = 0.0f;
#pragma unroll
        for (int ql = 0; ql < 4; ++ql) {
            t = fmaf(rdl_f(a0, ql), w2[4 * ql + 0], t);
            t = fmaf(rdl_f(a1, ql), w2[4 * ql + 1], t);
            t = fmaf(rdl_f(a2, ql), w2[4 * ql + 2], t);
            t = fmaf(rdl_f(a3, ql), w2[4 * ql + 3], t);
        }
        float r = fmaxf(fmaf(dg, t, bm), 0.0f);   // dg*(sum)@W2 + b2, relu
        outp[(long)g * 64 + lane] = __float2half(r * dg);  // pre-scaled fp16
    }
}

// ---------------- pull-gather, 64 ch fp16 (persistent, unroll-4): agg = dg*sum C ------
__global__ __launch_bounds__(256) void gather64h_k(const int* __restrict__ rowptr,
                                                   const int* __restrict__ csr_src,
                                                   const float* __restrict__ dinv,
                                                   const __half* __restrict__ hs,
                                                   __half* __restrict__ outp, int n) {
    const int lane = threadIdx.x & 63;
    const int wid = blockIdx.x * 4 + (threadIdx.x >> 6);
    const int nWaves = gridDim.x * 4;
    const int q = lane & 7;                 // uint4 chunk within 64-ch row
    const int sub = lane >> 3;              // edge subgroup 0..7
    const uint4* h4 = (const uint4*)hs;     // row = 8 chunks of 16B
    for (int g = wid; g < n; g += nWaves) {
        const float dg = dinv[g];
        const int beg = rowptr[g], end = rowptr[g + 1];
        float a[8];
#pragma unroll
        for (int i = 0; i < 8; ++i) a[i] = 0.f;
        if (sub == 0) {                      // self term
            uint4 v = h4[(long)g * 8 + q];
            h2acc(v.x, a[0], a[1]); h2acc(v.y, a[2], a[3]);
            h2acc(v.z, a[4], a[5]); h2acc(v.w, a[6], a[7]);
        }
        int j0 = beg;
        for (; j0 + 32 <= end; j0 += 32) {
            const int s0 = csr_src[j0 + sub];
            const int s1 = csr_src[j0 + 8 + sub];
            const int s2 = csr_src[j0 + 16 + sub];
            const int s3 = csr_src[j0 + 24 + sub];
            const uint4 v0 = h4[(long)s0 * 8 + q];
            const uint4 v1 = h4[(long)s1 * 8 + q];
            const uint4 v2 = h4[(long)s2 * 8 + q];
            const uint4 v3 = h4[(long)s3 * 8 + q];
            h2acc(v0.x, a[0], a[1]); h2acc(v0.y, a[2], a[3]);
            h2acc(v0.z, a[4], a[5]); h2acc(v0.w, a[6], a[7]);
            h2acc(v1.x, a[0], a[1]); h2acc(v1.y, a[2], a[3]);
            h2acc(v1.z, a[4], a[5]); h2acc(v1.w, a[6], a[7]);
            h2acc(v2.x, a[0], a[1]); h2acc(v2.y, a[2], a[3]);
            h2acc(v2.z, a[4], a[5]); h2acc(v2.w, a[6], a[7]);
            h2acc(v3.x, a[0], a[1]); h2acc(v3.y, a[2], a[3]);
            h2acc(v3.z, a[4], a[5]); h2acc(v3.w, a[6], a[7]);
        }
        for (; j0 + 8 <= end; j0 += 8) {
            const int s = csr_src[j0 + sub];
            const uint4 v = h4[(long)s * 8 + q];
            h2acc(v.x, a[0], a[1]); h2acc(v.y, a[2], a[3]);
            h2acc(v.z, a[4], a[5]); h2acc(v.w, a[6], a[7]);
        }
        if (j0 < end) {
            int idx = j0 + sub;
            if (idx < end) {
                const int s = csr_src[idx];
                const uint4 v = h4[(long)s * 8 + q];
                h2acc(v.x, a[0], a[1]); h2acc(v.y, a[2], a[3]);
                h2acc(v.z, a[4], a[5]); h2acc(v.w, a[6], a[7]);
            }
        }
#pragma unroll
        for (int m = 8; m <= 32; m <<= 1) {
#pragma unroll
            for (int i = 0; i < 8; ++i) a[i] += __shfl_xor(a[i], m, 64);
        }
        if (sub == 0) {
            uint4 w;
            w.x = packh2(a[0] * dg, a[1] * dg);
            w.y = packh2(a[2] * dg, a[3] * dg);
            w.z = packh2(a[4] * dg, a[5] * dg);
            w.w = packh2(a[6] * dg, a[7] * dg);
            ((uint4*)outp)[(long)g * 8 + q] = w;
        }
    }
}

// ---------------- MFMA head: out = relu(agg@W3 + b3).Wfc + bfc ----------------
// agg fp16 [N][64]; W3 cast fp16, staged in LDS in frag layout.
// mfma_f32_16x16x32_f16, ladder convention: A lane l -> (m=l&15, k=(l>>4)*8+j);
// B lane l -> (n=l&15, k=(l>>4)*8+j); C/D lane l reg i -> (row=(l>>4)*4+i, col=l&15).
// 16-node tile: 2 A-frags (k halves) x 8 outch-tiles = 16 MFMAs.
__global__ __launch_bounds__(256) void head_mfma_k(const __half* __restrict__ agg,
                                                   const float* __restrict__ W3,
                                                   const float* __restrict__ b3,
                                                   const float* __restrict__ Wfc,
                                                   const float* __restrict__ bfc,
                                                   float* __restrict__ out, int n) {
    __shared__ _Float16 sWf[8192];           // 16 KB, frag-layout
    const int tid = threadIdx.x;
    // stage: idx = ((th*64 + l)*8 + j), th = t*2+h; element = W3[k][nn],
    // k = (th&1)*32 + (l>>4)*8 + j, nn = (th>>1)*16 + (l&15)
    for (int i = tid; i < 8192; i += 256) {
        const int j = i & 7;
        const int l = (i >> 3) & 63;
        const int th = i >> 9;
        const int k = (th & 1) * 32 + ((l >> 4) << 3) + j;
        const int nn = (th >> 1) * 16 + (l & 15);
        sWf[i] = (_Float16)W3[k * 128 + nn];
    }
    __syncthreads();
    const int lane = tid & 63;
    const int wid = blockIdx.x * 4 + (tid >> 6);
    const int nWaves = gridDim.x * 4;
    const int col = lane & 15;
    const int kg = lane >> 4;
    half8 wf[16];
#pragma unroll
    for (int q2 = 0; q2 < 16; ++q2)
        wf[q2] = *((const half8*)&sWf[(q2 * 64 + lane) * 8]);
    float b3v[8], wfv[8];
#pragma unroll
    for (int t = 0; t < 8; ++t) {
        b3v[t] = b3[t * 16 + col];
        wfv[t] = Wfc[t * 16 + col];
    }
    const float bb = bfc[0];
    const int nTiles = n >> 4;               // 6250, exact
    union { uint4 u; half8 h; } cva, cvb;
    for (int tile = wid; tile < nTiles; tile += nWaves) {
        const int node0 = tile << 4;
        const uint4* rowp = (const uint4*)(agg + (long)(node0 + col) * 64);
        cva.u = rowp[kg];                     // k = kg*8 .. +8   (half 0)
        cvb.u = rowp[4 + kg];                 // k = 32 + kg*8..  (half 1)
        const half8 a0 = cva.h, a1 = cvb.h;
        f32x4 c[8];
#pragma unroll
        for (int t = 0; t < 8; ++t) {
            f32x4 z = {0.f, 0.f, 0.f, 0.f};
            c[t] = __builtin_amdgcn_mfma_f32_16x16x32_f16(a0, wf[t * 2], z, 0, 0, 0);
            c[t] = __builtin_amdgcn_mfma_f32_16x16x32_f16(a1, wf[t * 2 + 1], c[t], 0, 0, 0);
        }
        float s0 = 0.f, s1 = 0.f, s2 = 0.f, s3 = 0.f;
#pragma unroll
        for (int t = 0; t < 8; ++t) {
            s0 += fmaxf(c[t][0] + b3v[t], 0.f) * wfv[t];
            s1 += fmaxf(c[t][1] + b3v[t], 0.f) * wfv[t];
            s2 += fmaxf(c[t][2] + b3v[t], 0.f) * wfv[t];
            s3 += fmaxf(c[t][3] + b3v[t], 0.f) * wfv[t];
        }
#pragma unroll
        for (int m = 1; m <= 8; m <<= 1) {
            s0 += __shfl_xor(s0, m, 64);
            s1 += __shfl_xor(s1, m, 64);
            s2 += __shfl_xor(s2, m, 64);
            s3 += __shfl_xor(s3, m, 64);
        }
        if (col == 0) {
            const int nb = node0 + kg * 4;
            out[nb]     = s0 + bb;
            out[nb + 1] = s1 + bb;
            out[nb + 2] = s2 + bb;
            out[nb + 3] = s3 + bb;
        }
    }
}

extern "C" void kernel_launch(void* const* d_in, const int* in_sizes, int n_in,
                              void* d_out, int out_size, void* d_ws, size_t ws_size,
                              hipStream_t stream) {
    const float* x    = (const float*)d_in[0];
    const int*   ei   = (const int*)d_in[1];       // [2,E]: src = ei, dst = ei+E
    const float* W1   = (const float*)d_in[2];
    const float* b1   = (const float*)d_in[3];
    const float* W2   = (const float*)d_in[4];
    const float* b2   = (const float*)d_in[5];
    const float* W3   = (const float*)d_in[6];
    const float* b3   = (const float*)d_in[7];
    const float* Wfc  = (const float*)d_in[8];
    const float* bfc  = (const float*)d_in[9];
    float* out = (float*)d_out;

    const int* src = ei;
    const int* dst = ei + NE;

    // workspace layout (16B-aligned offsets; 4B units):
    // dinv[N] | rowptr[N+8] | mat[NBLK*NB2] | ofsT[NBLK*NB2] | colTotal[512]
    // | csr_src[E+64] | bucketed[E] u32
    // | A_h[16N] fp16 | B_h[16N] fp16 | C_h[64N] fp16 | agg_h[64N] fp16
    float* dinv        = (float*)d_ws;
    int*   rowptr      = (int*)(dinv + NN);
    int*   mat         = rowptr + NN + 8;
    int*   ofsT        = mat + NBLK * NB2 + 4;
    int*   colTotal    = ofsT + NBLK * NB2 + 4;
    int*   csr_src     = colTotal + 512;
    unsigned* bucketed = (unsigned*)(csr_src + NE + 64);
    __half* A_h        = (__half*)(bucketed + NE);
    __half* B_h        = A_h + (long)NN * 16;
    __half* C_h        = B_h + (long)NN * 16;
    __half* agg_h      = C_h + (long)NN * 64;

    const int T = 256;

    // ---- CSR build (atomic-free) + gemm1_raw overlapped ----
    const int gemmBlocks = (NN + 15) / 16;             // 6250
    count_gemm1_k<<<NBLK + gemmBlocks, T, 0, stream>>>(dst, mat, x, W1, A_h, NN);
    colscan_k<<<NB2, 64, 0, stream>>>(mat, ofsT, colTotal);
    p2_scatter_k<<<NBLK, 512, 0, stream>>>(src, dst, ofsT, colTotal, bucketed);
    p3_csr_k<<<NB2, 512, 0, stream>>>(bucketed, colTotal, rowptr, dinv, csr_src, A_h);

    // ---- B = dinv * relu(dg*(sum A) + b1)  (pre-scaled r1, 16ch fp16) ----
    gather16h_k<<<3072, T, 0, stream>>>(rowptr, csr_src, dinv, A_h, b1, B_h, NN);
    // ---- C = dinv * relu(dg*(sum B)@W2 + b2)  (pre-scaled r2, 64ch fp16) ----
    g16gemm2h_k<<<3072, T, 0, stream>>>(rowptr, csr_src, dinv, B_h, W2, b2, C_h, NN);
    // ---- agg(64ch fp16) = dg * sum C ----
    gather64h_k<<<3072, T, 0, stream>>>(rowptr, csr_src, dinv, C_h, agg_h, NN);
    // ---- head: out = relu(agg@W3 + b3).Wfc + bfc  (MFMA) ----
    head_mfma_k<<<256, T, 0, stream>>>(agg_h, W3, b3, Wfc, bfc, out, NN);
}

// Round 7
// 268.794 us; speedup vs baseline: 1.3858x; 1.0297x over previous
//
#include <hip/hip_runtime.h>
#include <hip/hip_fp16.h>

// GCN: N=100000, E=1600000, widths 128 -> 16 -> 64 -> 128 -> 1
// Round 18 (from 276.8us R17):
//  POST-MORTEM R17: gather64h unroll-4+persistent REGRESSED 49.8->57.2us
//  (VGPR 20->32, occ 72->61%, BW 3.49->3.09 TB/s) -- occupancy-for-ILP trade
//  loses on this latency-hiding-bound gather (same mechanism as R14 fusion).
//  -> REVERT gather64h to exact R16 form (block-per-node, unroll-2, 20 VGPR).
//  Keep R17 wins: gemm1 half2 LDS staging, MFMA head, persistent g16 grids.
//  NEW: p2_scatter batches 4 edges/thread/iter -> 4 independent
//  LDS-atomic->store chains (MLP), 4x fewer loop iterations.
// Pipeline: count+gemm1 -> colscan -> p2 -> p3
//           -> gather16(r1) -> g16gemm2(r2) -> gather64 -> head(MFMA).

#define NN 100000
#define NE 1600000
#define SHIFT 8                      // 256 nodes per bucket
#define NB2 391                      // ceil(NN/256)
#define EPB 4096                     // edges per P1/P2 block
#define NBLK 391                     // ceil(NE/EPB)
#define CHUNK 7                      // ceil(NBLK/64) for colscan

typedef _Float16 half8 __attribute__((ext_vector_type(8)));
typedef float f32x4 __attribute__((ext_vector_type(4)));

__device__ __forceinline__ float rdl_f(float v, int l) {
    return __int_as_float(__builtin_amdgcn_readlane(__float_as_int(v), l));
}

// unpack one half2 word, accumulate into two fp32 lanes
__device__ __forceinline__ void h2acc(unsigned u, float& a, float& b) {
    __half2 h = *reinterpret_cast<__half2*>(&u);
    float2 f = __half22float2(h);
    a += f.x; b += f.y;
}
__device__ __forceinline__ unsigned packh2(float a, float b) {
    __half2 h = __floats2half2_rn(a, b);
    return *reinterpret_cast<unsigned*>(&h);
}
__device__ __forceinline__ unsigned sc2(unsigned u, float s) {
    __half2 h = *reinterpret_cast<__half2*>(&u);
    float2 f = __half22float2(h);
    return packh2(f.x * s, f.y * s);
}

// ---------------- P1: bucket counts (blocks < NBLK) + gemm1_raw (rest) ----------------
// gemm1_raw: A = x @ W1 (unscaled; dinv applied in P3), K=128, M=16, fp16 out.
// half2-staged LDS: 1 LDS read per 2 MACs on each operand.
__global__ __launch_bounds__(256) void count_gemm1_k(const int* __restrict__ dst,
                                                     int* __restrict__ mat,
                                                     const float* __restrict__ x,
                                                     const float* __restrict__ W1,
                                                     __half* __restrict__ A, int n) {
    __shared__ int cnt[NB2];
    __shared__ unsigned sW2[64 * 16];        // half2[k2][m]
    __shared__ unsigned sIn2[16][66];        // half2 row chunks, +2 pad
    const int tid = threadIdx.x;
    if ((int)blockIdx.x < NBLK) {
        for (int i = tid; i < NB2; i += 256) cnt[i] = 0;
        __syncthreads();
        const int e0 = blockIdx.x * EPB;
        const int e1 = min(e0 + EPB, NE);
        for (int i = e0 + tid; i < e1; i += 256) atomicAdd(&cnt[dst[i] >> SHIFT], 1);
        __syncthreads();
        for (int c = tid; c < NB2; c += 256) mat[blockIdx.x * NB2 + c] = cnt[c];
        return;
    }
    const int bid = blockIdx.x - NBLK;
    for (int i = tid; i < 64 * 16; i += 256) {
        const int k2 = i >> 4, m = i & 15;
        sW2[i] = packh2(W1[(2 * k2) * 16 + m], W1[(2 * k2 + 1) * 16 + m]);
    }
    const int row0 = bid * 16;
    const float4* in4 = (const float4*)x;
    for (int i = tid; i < 16 * 32; i += 256) {
        int r = i >> 5, kv = i & 31;
        int g = row0 + r;
        float4 v = make_float4(0.f, 0.f, 0.f, 0.f);
        if (g < n) v = in4[(long)g * 32 + kv];
        sIn2[r][kv * 2]     = packh2(v.x, v.y);
        sIn2[r][kv * 2 + 1] = packh2(v.z, v.w);
    }
    __syncthreads();
    const int r = tid >> 4, m = tid & 15;
    const int g = row0 + r;
    if (g < n) {
        float acc = 0.0f;
#pragma unroll
        for (int k2 = 0; k2 < 64; ++k2) {
            const __half2 a = *reinterpret_cast<const __half2*>(&sIn2[r][k2]);
            const __half2 w = *reinterpret_cast<const __half2*>(&sW2[k2 * 16 + m]);
            const float2 af = __half22float2(a);
            const float2 wf = __half22float2(w);
            acc = fmaf(af.x, wf.x, acc);
            acc = fmaf(af.y, wf.y, acc);
        }
        A[(long)g * 16 + m] = __float2half(acc);
    }
}

// ---------------- colscan: per-bucket exclusive scan over edge-blocks ----------------
__global__ __launch_bounds__(64) void colscan_k(const int* __restrict__ mat,
                                                int* __restrict__ ofsT,
                                                int* __restrict__ colTotal) {
    const int c = blockIdx.x;
    const int lane = threadIdx.x;
    int v[CHUNK];
    int s = 0;
    const int base = lane * CHUNK;
#pragma unroll
    for (int j = 0; j < CHUNK; ++j) {
        int b = base + j;
        int x_ = (b < NBLK) ? mat[b * NB2 + c] : 0;
        v[j] = s;              // local exclusive prefix
        s += x_;
    }
    int inc = s;
#pragma unroll
    for (int d = 1; d < 64; d <<= 1) {
        int t = __shfl_up(inc, d, 64);
        if (lane >= d) inc += t;
    }
    const int excl = inc - s;
#pragma unroll
    for (int j = 0; j < CHUNK; ++j) {
        int b = base + j;
        if (b < NBLK) ofsT[b * NB2 + c] = excl + v[j];
    }
    if (lane == 63) colTotal[c] = excl + s;
}

// ---------------- P2: scatter packed edges into bucket regions ----------------
// 4-edge batched reads: 4 independent LDS-atomic->store chains per thread.
__global__ __launch_bounds__(512) void p2_scatter_k(const int* __restrict__ src,
                                                    const int* __restrict__ dst,
                                                    const int* __restrict__ ofsT,
                                                    const int* __restrict__ colTotal,
                                                    unsigned* __restrict__ bucketed) {
    __shared__ int sc[512];
    __shared__ int cur[NB2];
    const int b = blockIdx.x;
    const int t = threadIdx.x;
    int v = (t < NB2) ? colTotal[t] : 0;
    sc[t] = v;
    __syncthreads();
    for (int off = 1; off < 512; off <<= 1) {
        int a = (t >= off) ? sc[t - off] : 0;
        __syncthreads();
        sc[t] += a;
        __syncthreads();
    }
    if (t < NB2) cur[t] = (sc[t] - v) + ofsT[b * NB2 + t];
    __syncthreads();
    const int e0 = b * EPB;
    const int e1 = min(e0 + EPB, NE);
    // EPB=4096, 512 threads -> exactly 2 batched iterations of 4 when full.
    int i = e0 + t * 4;
    const int stride = 512 * 4;
    for (; i + 3 < e1; i += stride) {
        const int d0 = dst[i], d1 = dst[i + 1], d2 = dst[i + 2], d3 = dst[i + 3];
        const int s0 = src[i], s1 = src[i + 1], s2 = src[i + 2], s3 = src[i + 3];
        const int c0 = d0 >> SHIFT, c1 = d1 >> SHIFT;
        const int c2 = d2 >> SHIFT, c3 = d3 >> SHIFT;
        const int p0 = atomicAdd(&cur[c0], 1);
        const int p1 = atomicAdd(&cur[c1], 1);
        const int p2 = atomicAdd(&cur[c2], 1);
        const int p3 = atomicAdd(&cur[c3], 1);
        bucketed[p0] = ((unsigned)s0 << 8) | (unsigned)(d0 & 255);
        bucketed[p1] = ((unsigned)s1 << 8) | (unsigned)(d1 & 255);
        bucketed[p2] = ((unsigned)s2 << 8) | (unsigned)(d2 & 255);
        bucketed[p3] = ((unsigned)s3 << 8) | (unsigned)(d3 & 255);
    }
    for (; i < e1; ++i) {
        const int d = dst[i];
        const int c = d >> SHIFT;
        const int pos = atomicAdd(&cur[c], 1);
        bucketed[pos] = ((unsigned)src[i] << 8) | (unsigned)(d & 255);
    }
}

// ---------------- P3: per-bucket CSR (rowptr, dinv, csr_src) + A rescale ----------------
__global__ __launch_bounds__(512) void p3_csr_k(const unsigned* __restrict__ bucketed,
                                                const int* __restrict__ colTotal,
                                                int* __restrict__ rowptr,
                                                float* __restrict__ dinv,
                                                int* __restrict__ csr_src,
                                                __half* __restrict__ A) {
    __shared__ int sc[512];
    __shared__ int cnt[256];
    __shared__ int excl[256];
    __shared__ float ld[256];
    const int c = blockIdx.x;
    const int t = threadIdx.x;
    int v = (t < NB2) ? colTotal[t] : 0;
    sc[t] = v;
    if (t < 256) cnt[t] = 0;
    __syncthreads();
    for (int off = 1; off < 512; off <<= 1) {
        int a = (t >= off) ? sc[t - off] : 0;
        __syncthreads();
        sc[t] += a;
        __syncthreads();
    }
    const int end  = sc[c];
    const int base = (c > 0) ? sc[c - 1] : 0;
    for (int i = base + t; i < end; i += 512) atomicAdd(&cnt[bucketed[i] & 255u], 1);
    __syncthreads();
    if (t < 256) excl[t] = cnt[t];
    __syncthreads();
    for (int off = 1; off < 256; off <<= 1) {
        int a = (t < 256 && t >= off) ? excl[t - off] : 0;
        __syncthreads();
        if (t < 256) excl[t] += a;
        __syncthreads();
    }
    const int node0 = c << SHIFT;
    if (t < 256) {
        const int node = node0 + t;
        const int ex = excl[t] - cnt[t];
        if (node < NN) {
            rowptr[node] = base + ex;
            const float dv = rsqrtf((float)cnt[t] + 1.0f);  // +1 self loop
            dinv[node] = dv;
            ld[t] = dv;
        }
        excl[t] = ex;  // becomes the fill cursor
    }
    if (c == NB2 - 1 && t == 0) rowptr[NN] = NE;
    __syncthreads();
    for (int i = base + t; i < end; i += 512) {
        const unsigned p = bucketed[i];
        const int pos = atomicAdd(&excl[p & 255u], 1);
        csr_src[base + pos] = (int)(p >> 8);
    }
    {
        const int node = node0 + (t >> 1);
        if (node < NN) {
            const float dv = ld[t >> 1];
            uint4* p = (uint4*)(A + (long)node * 16 + (t & 1) * 8);
            uint4 q = *p;
            q.x = sc2(q.x, dv); q.y = sc2(q.y, dv);
            q.z = sc2(q.z, dv); q.w = sc2(q.w, dv);
            *p = q;
        }
    }
}

// ---------------- pull-gather, 16 ch fp16 (persistent): B = dinv*relu(dg*(sum A)+b1) ----
__global__ __launch_bounds__(256) void gather16h_k(const int* __restrict__ rowptr,
                                                   const int* __restrict__ csr_src,
                                                   const float* __restrict__ dinv,
                                                   const __half* __restrict__ hs,
                                                   const float* __restrict__ bias,
                                                   __half* __restrict__ outp, int n) {
    const int lane = threadIdx.x & 63;
    const int wid0 = blockIdx.x * 4 + (threadIdx.x >> 6);
    const int nWaves = gridDim.x * 4;
    const int q = lane & 3;                 // uint2 chunk within 16-ch row
    const int sub = lane >> 2;              // edge subgroup 0..15
    const uint2* h2p = (const uint2*)hs;
    const float4 b = ((const float4*)bias)[q];
    for (int g = wid0; g < n; g += nWaves) {
        const float dg = dinv[g];
        const int beg = rowptr[g], end = rowptr[g + 1];
        float a0 = 0.f, a1 = 0.f, a2 = 0.f, a3 = 0.f;
        if (sub == 0) {                      // self term
            uint2 v = h2p[(long)g * 4 + q];
            h2acc(v.x, a0, a1); h2acc(v.y, a2, a3);
        }
        for (int j0 = beg; j0 < end; j0 += 16) {
            int idx = j0 + sub;
            if (idx < end) {
                const int s = csr_src[idx];
                uint2 v = h2p[(long)s * 4 + q];
                h2acc(v.x, a0, a1); h2acc(v.y, a2, a3);
            }
        }
#pragma unroll
        for (int m = 4; m <= 32; m <<= 1) {
            a0 += __shfl_xor(a0, m, 64);
            a1 += __shfl_xor(a1, m, 64);
            a2 += __shfl_xor(a2, m, 64);
            a3 += __shfl_xor(a3, m, 64);
        }
        if (sub == 0) {
            float v0 = fmaxf(fmaf(dg, a0, b.x), 0.0f) * dg;
            float v1 = fmaxf(fmaf(dg, a1, b.y), 0.0f) * dg;
            float v2 = fmaxf(fmaf(dg, a2, b.z), 0.0f) * dg;
            float v3 = fmaxf(fmaf(dg, a3, b.w), 0.0f) * dg;
            uint2 w;
            w.x = packh2(v0, v1);
            w.y = packh2(v2, v3);
            ((uint2*)outp)[(long)g * 4 + q] = w;
        }
    }
}

// ---------------- fused gather16 + gemm2: C = dinv*relu(dg*(sum B)@W2 + b2), fp16 out ----
__global__ __launch_bounds__(256) void g16gemm2h_k(const int* __restrict__ rowptr,
                                                   const int* __restrict__ csr_src,
                                                   const float* __restrict__ dinv,
                                                   const __half* __restrict__ hs,
                                                   const float* __restrict__ W2,
                                                   const float* __restrict__ b2,
                                                   __half* __restrict__ outp, int n) {
    const int lane = threadIdx.x & 63;
    const int wid = blockIdx.x * 4 + (threadIdx.x >> 6);
    const int nWaves = gridDim.x * 4;
    float w2[16];
#pragma unroll
    for (int k = 0; k < 16; ++k) w2[k] = W2[k * 64 + lane];
    const float bm = b2[lane];
    const int q = lane & 3;
    const int sub = lane >> 2;
    const uint2* h2p = (const uint2*)hs;
    for (int g = wid; g < n; g += nWaves) {
        const float dg = dinv[g];
        const int beg = rowptr[g], end = rowptr[g + 1];
        float a0 = 0.f, a1 = 0.f, a2 = 0.f, a3 = 0.f;
        if (sub == 0) {                      // self term
            uint2 v = h2p[(long)g * 4 + q];
            h2acc(v.x, a0, a1); h2acc(v.y, a2, a3);
        }
        for (int j0 = beg; j0 < end; j0 += 16) {
            int idx = j0 + sub;
            if (idx < end) {
                const int s = csr_src[idx];
                uint2 v = h2p[(long)s * 4 + q];
                h2acc(v.x, a0, a1); h2acc(v.y, a2, a3);
            }
        }
#pragma unroll
        for (int m = 4; m <= 32; m <<= 1) {
            a0 += __shfl_xor(a0, m, 64);
            a1 += __shfl_xor(a1, m, 64);
            a2 += __shfl_xor(a2, m, 64);
            a3 += __shfl_xor(a3, m, 64);
        }
        float t = 0.0f;
#pragma unroll
        for (int ql = 0; ql < 4; ++ql) {
            t = fmaf(rdl_f(a0, ql), w2[4 * ql + 0], t);
            t = fmaf(rdl_f(a1, ql), w2[4 * ql + 1], t);
            t = fmaf(rdl_f(a2, ql), w2[4 * ql + 2], t);
            t = fmaf(rdl_f(a3, ql), w2[4 * ql + 3], t);
        }
        float r = fmaxf(fmaf(dg, t, bm), 0.0f);   // dg*(sum)@W2 + b2, relu
        outp[(long)g * 64 + lane] = __float2half(r * dg);  // pre-scaled fp16
    }
}

// ---------------- pull-gather, 64 ch fp16 (R16 exact): agg = dg * sum C ----------------
// 8 lanes x uint4 (16B) per 128B row (exactly one cache line per edge).
__global__ __launch_bounds__(256) void gather64h_k(const int* __restrict__ rowptr,
                                                   const int* __restrict__ csr_src,
                                                   const float* __restrict__ dinv,
                                                   const __half* __restrict__ hs,
                                                   __half* __restrict__ outp, int n) {
    const int g = (blockIdx.x * 256 + threadIdx.x) >> 6;
    if (g >= n) return;
    const int lane = threadIdx.x & 63;
    const int q = lane & 7;                 // uint4 chunk within 64-ch row
    const int sub = lane >> 3;              // edge subgroup 0..7
    const float dg = dinv[g];
    const int beg = rowptr[g], end = rowptr[g + 1];
    const uint4* h4 = (const uint4*)hs;     // row = 8 chunks of 16B
    float a[8];
#pragma unroll
    for (int i = 0; i < 8; ++i) a[i] = 0.f;
    if (sub == 0) {                          // self term
        uint4 v = h4[(long)g * 8 + q];
        h2acc(v.x, a[0], a[1]); h2acc(v.y, a[2], a[3]);
        h2acc(v.z, a[4], a[5]); h2acc(v.w, a[6], a[7]);
    }
    int j0 = beg;
    for (; j0 + 16 <= end; j0 += 16) {
        const int s0 = csr_src[j0 + sub];
        const int s1 = csr_src[j0 + 8 + sub];
        const uint4 v0 = h4[(long)s0 * 8 + q];
        const uint4 v1 = h4[(long)s1 * 8 + q];
        h2acc(v0.x, a[0], a[1]); h2acc(v0.y, a[2], a[3]);
        h2acc(v0.z, a[4], a[5]); h2acc(v0.w, a[6], a[7]);
        h2acc(v1.x, a[0], a[1]); h2acc(v1.y, a[2], a[3]);
        h2acc(v1.z, a[4], a[5]); h2acc(v1.w, a[6], a[7]);
    }
    for (; j0 < end; j0 += 8) {
        int idx = j0 + sub;
        if (idx < end) {
            const int s = csr_src[idx];
            const uint4 v = h4[(long)s * 8 + q];
            h2acc(v.x, a[0], a[1]); h2acc(v.y, a[2], a[3]);
            h2acc(v.z, a[4], a[5]); h2acc(v.w, a[6], a[7]);
        }
    }
#pragma unroll
    for (int m = 8; m <= 32; m <<= 1) {
#pragma unroll
        for (int i = 0; i < 8; ++i) a[i] += __shfl_xor(a[i], m, 64);
    }
    if (sub == 0) {
        uint4 w;
        w.x = packh2(a[0] * dg, a[1] * dg);
        w.y = packh2(a[2] * dg, a[3] * dg);
        w.z = packh2(a[4] * dg, a[5] * dg);
        w.w = packh2(a[6] * dg, a[7] * dg);
        ((uint4*)outp)[(long)g * 8 + q] = w;
    }
}

// ---------------- MFMA head: out = relu(agg@W3 + b3).Wfc + bfc ----------------
// agg fp16 [N][64]; W3 cast fp16, staged in LDS in frag layout.
// mfma_f32_16x16x32_f16; 16-node tile: 2 A-frags (k halves) x 8 outch-tiles.
__global__ __launch_bounds__(256) void head_mfma_k(const __half* __restrict__ agg,
                                                   const float* __restrict__ W3,
                                                   const float* __restrict__ b3,
                                                   const float* __restrict__ Wfc,
                                                   const float* __restrict__ bfc,
                                                   float* __restrict__ out, int n) {
    __shared__ _Float16 sWf[8192];           // 16 KB, frag-layout
    const int tid = threadIdx.x;
    for (int i = tid; i < 8192; i += 256) {
        const int j = i & 7;
        const int l = (i >> 3) & 63;
        const int th = i >> 9;
        const int k = (th & 1) * 32 + ((l >> 4) << 3) + j;
        const int nn = (th >> 1) * 16 + (l & 15);
        sWf[i] = (_Float16)W3[k * 128 + nn];
    }
    __syncthreads();
    const int lane = tid & 63;
    const int wid = blockIdx.x * 4 + (tid >> 6);
    const int nWaves = gridDim.x * 4;
    const int col = lane & 15;
    const int kg = lane >> 4;
    half8 wf[16];
#pragma unroll
    for (int q2 = 0; q2 < 16; ++q2)
        wf[q2] = *((const half8*)&sWf[(q2 * 64 + lane) * 8]);
    float b3v[8], wfv[8];
#pragma unroll
    for (int t = 0; t < 8; ++t) {
        b3v[t] = b3[t * 16 + col];
        wfv[t] = Wfc[t * 16 + col];
    }
    const float bb = bfc[0];
    const int nTiles = n >> 4;               // 6250, exact
    union { uint4 u; half8 h; } cva, cvb;
    for (int tile = wid; tile < nTiles; tile += nWaves) {
        const int node0 = tile << 4;
        const uint4* rowp = (const uint4*)(agg + (long)(node0 + col) * 64);
        cva.u = rowp[kg];                     // k = kg*8 .. +8   (half 0)
        cvb.u = rowp[4 + kg];                 // k = 32 + kg*8..  (half 1)
        const half8 a0 = cva.h, a1 = cvb.h;
        f32x4 c[8];
#pragma unroll
        for (int t = 0; t < 8; ++t) {
            f32x4 z = {0.f, 0.f, 0.f, 0.f};
            c[t] = __builtin_amdgcn_mfma_f32_16x16x32_f16(a0, wf[t * 2], z, 0, 0, 0);
            c[t] = __builtin_amdgcn_mfma_f32_16x16x32_f16(a1, wf[t * 2 + 1], c[t], 0, 0, 0);
        }
        float s0 = 0.f, s1 = 0.f, s2 = 0.f, s3 = 0.f;
#pragma unroll
        for (int t = 0; t < 8; ++t) {
            s0 += fmaxf(c[t][0] + b3v[t], 0.f) * wfv[t];
            s1 += fmaxf(c[t][1] + b3v[t], 0.f) * wfv[t];
            s2 += fmaxf(c[t][2] + b3v[t], 0.f) * wfv[t];
            s3 += fmaxf(c[t][3] + b3v[t], 0.f) * wfv[t];
        }
#pragma unroll
        for (int m = 1; m <= 8; m <<= 1) {
            s0 += __shfl_xor(s0, m, 64);
            s1 += __shfl_xor(s1, m, 64);
            s2 += __shfl_xor(s2, m, 64);
            s3 += __shfl_xor(s3, m, 64);
        }
        if (col == 0) {
            const int nb = node0 + kg * 4;
            out[nb]     = s0 + bb;
            out[nb + 1] = s1 + bb;
            out[nb + 2] = s2 + bb;
            out[nb + 3] = s3 + bb;
        }
    }
}

extern "C" void kernel_launch(void* const* d_in, const int* in_sizes, int n_in,
                              void* d_out, int out_size, void* d_ws, size_t ws_size,
                              hipStream_t stream) {
    const float* x    = (const float*)d_in[0];
    const int*   ei   = (const int*)d_in[1];       // [2,E]: src = ei, dst = ei+E
    const float* W1   = (const float*)d_in[2];
    const float* b1   = (const float*)d_in[3];
    const float* W2   = (const float*)d_in[4];
    const float* b2   = (const float*)d_in[5];
    const float* W3   = (const float*)d_in[6];
    const float* b3   = (const float*)d_in[7];
    const float* Wfc  = (const float*)d_in[8];
    const float* bfc  = (const float*)d_in[9];
    float* out = (float*)d_out;

    const int* src = ei;
    const int* dst = ei + NE;

    // workspace layout (16B-aligned offsets; 4B units):
    // dinv[N] | rowptr[N+8] | mat[NBLK*NB2] | ofsT[NBLK*NB2] | colTotal[512]
    // | csr_src[E+64] | bucketed[E] u32
    // | A_h[16N] fp16 | B_h[16N] fp16 | C_h[64N] fp16 | agg_h[64N] fp16
    float* dinv        = (float*)d_ws;
    int*   rowptr      = (int*)(dinv + NN);
    int*   mat         = rowptr + NN + 8;
    int*   ofsT        = mat + NBLK * NB2 + 4;
    int*   colTotal    = ofsT + NBLK * NB2 + 4;
    int*   csr_src     = colTotal + 512;
    unsigned* bucketed = (unsigned*)(csr_src + NE + 64);
    __half* A_h        = (__half*)(bucketed + NE);
    __half* B_h        = A_h + (long)NN * 16;
    __half* C_h        = B_h + (long)NN * 16;
    __half* agg_h      = C_h + (long)NN * 64;

    const int T = 256;

    // ---- CSR build (atomic-free) + gemm1_raw overlapped ----
    const int gemmBlocks = (NN + 15) / 16;             // 6250
    count_gemm1_k<<<NBLK + gemmBlocks, T, 0, stream>>>(dst, mat, x, W1, A_h, NN);
    colscan_k<<<NB2, 64, 0, stream>>>(mat, ofsT, colTotal);
    p2_scatter_k<<<NBLK, 512, 0, stream>>>(src, dst, ofsT, colTotal, bucketed);
    p3_csr_k<<<NB2, 512, 0, stream>>>(bucketed, colTotal, rowptr, dinv, csr_src, A_h);

    // ---- B = dinv * relu(dg*(sum A) + b1)  (pre-scaled r1, 16ch fp16) ----
    gather16h_k<<<3072, T, 0, stream>>>(rowptr, csr_src, dinv, A_h, b1, B_h, NN);
    // ---- C = dinv * relu(dg*(sum B)@W2 + b2)  (pre-scaled r2, 64ch fp16) ----
    g16gemm2h_k<<<3072, T, 0, stream>>>(rowptr, csr_src, dinv, B_h, W2, b2, C_h, NN);
    // ---- agg(64ch fp16) = dg * sum C ----
    gather64h_k<<<(NN + 3) / 4, T, 0, stream>>>(rowptr, csr_src, dinv, C_h, agg_h, NN);
    // ---- head: out = relu(agg@W3 + b3).Wfc + bfc  (MFMA) ----
    head_mfma_k<<<256, T, 0, stream>>>(agg_h, W3, b3, Wfc, bfc, out, NN);
}

// Round 8
// 265.794 us; speedup vs baseline: 1.4014x; 1.0113x over previous
//
#include <hip/hip_runtime.h>
#include <hip/hip_fp16.h>

// GCN: N=100000, E=1600000, widths 128 -> 16 -> 64 -> 128 -> 1
// Round 19 (from 268.8us R18):
//  (1) gemm1 -> MFMA (mfma_f32_16x16x32_f16, same verified frag convention
//      as head_mfma): 64 nodes/block, x-tile + W1 staged fp16 in LDS
//      (x-tile rows padded to 136 halves -> 2 lanes/bank, free). Replaces
//      128 serial FMAs/thread (~20us LDS+VALU-bound) with 4 chained
//      MFMAs/wave -> x-read-BW-bound (~10-12us).
//  (2) p2 block 0 publishes bucketBase; p3 drops its 512-wide scan
//      (18 barriers on a latency-bound 391-block dispatch).
//  gather64h FROZEN at R16 shape (block-per-node, unroll-2): R17 showed
//  persistent-grid tail imbalance costs ~7us; it runs within ~7% of the
//  fetch-path line-rate ceiling for a 12.8MB set in 4MiB/XCD L2.
// Pipeline: count+gemm1(MFMA) -> colscan -> p2 -> p3
//           -> gather16(r1) -> g16gemm2(r2) -> gather64 -> head(MFMA).

#define NN 100000
#define NE 1600000
#define SHIFT 8                      // 256 nodes per bucket
#define NB2 391                      // ceil(NN/256)
#define EPB 4096                     // edges per P1/P2 block
#define NBLK 391                     // ceil(NE/EPB)
#define CHUNK 7                      // ceil(NBLK/64) for colscan

typedef _Float16 half8 __attribute__((ext_vector_type(8)));
typedef float f32x4 __attribute__((ext_vector_type(4)));

__device__ __forceinline__ float rdl_f(float v, int l) {
    return __int_as_float(__builtin_amdgcn_readlane(__float_as_int(v), l));
}

// unpack one half2 word, accumulate into two fp32 lanes
__device__ __forceinline__ void h2acc(unsigned u, float& a, float& b) {
    __half2 h = *reinterpret_cast<__half2*>(&u);
    float2 f = __half22float2(h);
    a += f.x; b += f.y;
}
__device__ __forceinline__ unsigned packh2(float a, float b) {
    __half2 h = __floats2half2_rn(a, b);
    return *reinterpret_cast<unsigned*>(&h);
}
__device__ __forceinline__ unsigned sc2(unsigned u, float s) {
    __half2 h = *reinterpret_cast<__half2*>(&u);
    float2 f = __half22float2(h);
    return packh2(f.x * s, f.y * s);
}

// ---------------- P1: bucket counts (blocks < NBLK) + MFMA gemm1 (rest) ----------------
// gemm1_raw: A = x @ W1 (unscaled; dinv applied in P3), K=128, M=16, fp16 out.
// 64 nodes per block (4 waves x 16-node tile), 4 chained MFMAs per wave.
__global__ __launch_bounds__(256) void count_gemm1_k(const int* __restrict__ dst,
                                                     int* __restrict__ mat,
                                                     const float* __restrict__ x,
                                                     const float* __restrict__ W1,
                                                     __half* __restrict__ A, int n) {
    __shared__ int cnt[NB2];
    __shared__ _Float16 sW1f[2048];          // 4 k-tiles x 64 lanes x 8 (frag layout)
    __shared__ unsigned sxu[4][16][68];      // per-wave fp16 x-tile, 136-half rows
    const int tid = threadIdx.x;
    if ((int)blockIdx.x < NBLK) {
        for (int i = tid; i < NB2; i += 256) cnt[i] = 0;
        __syncthreads();
        const int e0 = blockIdx.x * EPB;
        const int e1 = min(e0 + EPB, NE);
        for (int i = e0 + tid; i < e1; i += 256) atomicAdd(&cnt[dst[i] >> SHIFT], 1);
        __syncthreads();
        for (int c = tid; c < NB2; c += 256) mat[blockIdx.x * NB2 + c] = cnt[c];
        return;
    }
    const int bid = blockIdx.x - NBLK;
    const int row0 = bid * 64;
    // stage W1 frags: i = kt*512 + l*8 + j -> W1[kt*32 + (l>>4)*8 + j][l&15]
    for (int i = tid; i < 2048; i += 256) {
        const int kt = i >> 9;
        const int l = (i >> 3) & 63;
        const int j = i & 7;
        const int k = kt * 32 + ((l >> 4) << 3) + j;
        sW1f[i] = (_Float16)W1[k * 16 + (l & 15)];
    }
    // stage x rows (64 x 128 f32 -> fp16)
    const float4* in4 = (const float4*)x;
    for (int i = tid; i < 2048; i += 256) {
        const int r = i >> 5, kv = i & 31;
        const int g = row0 + r;
        float4 v = make_float4(0.f, 0.f, 0.f, 0.f);
        if (g < n) v = in4[(long)g * 32 + kv];
        unsigned* su = &sxu[r >> 4][r & 15][0];
        su[kv * 2]     = packh2(v.x, v.y);
        su[kv * 2 + 1] = packh2(v.z, v.w);
    }
    __syncthreads();
    const int w = tid >> 6, l = tid & 63;
    const int node0 = row0 + w * 16;
    f32x4 c = {0.f, 0.f, 0.f, 0.f};
#pragma unroll
    for (int kt = 0; kt < 4; ++kt) {
        const half8 a = *(const half8*)&sxu[w][l & 15][kt * 16 + ((l >> 4) << 2)];
        const half8 b = *(const half8*)&sW1f[kt * 512 + l * 8];
        c = __builtin_amdgcn_mfma_f32_16x16x32_f16(a, b, c, 0, 0, 0);
    }
#pragma unroll
    for (int i = 0; i < 4; ++i) {
        const int g = node0 + ((l >> 4) << 2) + i;
        if (g < n) A[(long)g * 16 + (l & 15)] = __float2half(c[i]);
    }
}

// ---------------- colscan: per-bucket exclusive scan over edge-blocks ----------------
__global__ __launch_bounds__(64) void colscan_k(const int* __restrict__ mat,
                                                int* __restrict__ ofsT,
                                                int* __restrict__ colTotal) {
    const int c = blockIdx.x;
    const int lane = threadIdx.x;
    int v[CHUNK];
    int s = 0;
    const int base = lane * CHUNK;
#pragma unroll
    for (int j = 0; j < CHUNK; ++j) {
        int b = base + j;
        int x_ = (b < NBLK) ? mat[b * NB2 + c] : 0;
        v[j] = s;              // local exclusive prefix
        s += x_;
    }
    int inc = s;
#pragma unroll
    for (int d = 1; d < 64; d <<= 1) {
        int t = __shfl_up(inc, d, 64);
        if (lane >= d) inc += t;
    }
    const int excl = inc - s;
#pragma unroll
    for (int j = 0; j < CHUNK; ++j) {
        int b = base + j;
        if (b < NBLK) ofsT[b * NB2 + c] = excl + v[j];
    }
    if (lane == 63) colTotal[c] = excl + s;
}

// ---------------- P2: scatter packed edges; block 0 publishes bucketBase -------------
__global__ __launch_bounds__(512) void p2_scatter_k(const int* __restrict__ src,
                                                    const int* __restrict__ dst,
                                                    const int* __restrict__ ofsT,
                                                    const int* __restrict__ colTotal,
                                                    int* __restrict__ bucketBase,
                                                    unsigned* __restrict__ bucketed) {
    __shared__ int sc[512];
    __shared__ int cur[NB2];
    const int b = blockIdx.x;
    const int t = threadIdx.x;
    int v = (t < NB2) ? colTotal[t] : 0;
    sc[t] = v;
    __syncthreads();
    for (int off = 1; off < 512; off <<= 1) {
        int a = (t >= off) ? sc[t - off] : 0;
        __syncthreads();
        sc[t] += a;
        __syncthreads();
    }
    if (t < NB2) cur[t] = (sc[t] - v) + ofsT[b * NB2 + t];
    if (b == 0) {
        if (t < NB2) bucketBase[t] = sc[t] - v;
        if (t == NB2) bucketBase[NB2] = NE;
    }
    __syncthreads();
    const int e0 = b * EPB;
    const int e1 = min(e0 + EPB, NE);
    int i = e0 + t * 4;
    const int stride = 512 * 4;
    for (; i + 3 < e1; i += stride) {
        const int d0 = dst[i], d1 = dst[i + 1], d2 = dst[i + 2], d3 = dst[i + 3];
        const int s0 = src[i], s1 = src[i + 1], s2 = src[i + 2], s3 = src[i + 3];
        const int c0 = d0 >> SHIFT, c1 = d1 >> SHIFT;
        const int c2 = d2 >> SHIFT, c3 = d3 >> SHIFT;
        const int p0 = atomicAdd(&cur[c0], 1);
        const int p1 = atomicAdd(&cur[c1], 1);
        const int p2 = atomicAdd(&cur[c2], 1);
        const int p3 = atomicAdd(&cur[c3], 1);
        bucketed[p0] = ((unsigned)s0 << 8) | (unsigned)(d0 & 255);
        bucketed[p1] = ((unsigned)s1 << 8) | (unsigned)(d1 & 255);
        bucketed[p2] = ((unsigned)s2 << 8) | (unsigned)(d2 & 255);
        bucketed[p3] = ((unsigned)s3 << 8) | (unsigned)(d3 & 255);
    }
    for (; i < e1; ++i) {
        const int d = dst[i];
        const int c = d >> SHIFT;
        const int pos = atomicAdd(&cur[c], 1);
        bucketed[pos] = ((unsigned)src[i] << 8) | (unsigned)(d & 255);
    }
}

// ---------------- P3: per-bucket CSR (rowptr, dinv, csr_src) + A rescale ----------------
__global__ __launch_bounds__(512) void p3_csr_k(const unsigned* __restrict__ bucketed,
                                                const int* __restrict__ bucketBase,
                                                int* __restrict__ rowptr,
                                                float* __restrict__ dinv,
                                                int* __restrict__ csr_src,
                                                __half* __restrict__ A) {
    __shared__ int cnt[256];
    __shared__ int excl[256];
    __shared__ float ld[256];
    const int c = blockIdx.x;
    const int t = threadIdx.x;
    const int base = bucketBase[c];
    const int end  = bucketBase[c + 1];
    if (t < 256) cnt[t] = 0;
    __syncthreads();
    for (int i = base + t; i < end; i += 512) atomicAdd(&cnt[bucketed[i] & 255u], 1);
    __syncthreads();
    if (t < 256) excl[t] = cnt[t];
    __syncthreads();
    for (int off = 1; off < 256; off <<= 1) {
        int a = (t < 256 && t >= off) ? excl[t - off] : 0;
        __syncthreads();
        if (t < 256) excl[t] += a;
        __syncthreads();
    }
    const int node0 = c << SHIFT;
    if (t < 256) {
        const int node = node0 + t;
        const int ex = excl[t] - cnt[t];
        if (node < NN) {
            rowptr[node] = base + ex;
            const float dv = rsqrtf((float)cnt[t] + 1.0f);  // +1 self loop
            dinv[node] = dv;
            ld[t] = dv;
        }
        excl[t] = ex;  // becomes the fill cursor
    }
    if (c == NB2 - 1 && t == 0) rowptr[NN] = NE;
    __syncthreads();
    for (int i = base + t; i < end; i += 512) {
        const unsigned p = bucketed[i];
        const int pos = atomicAdd(&excl[p & 255u], 1);
        csr_src[base + pos] = (int)(p >> 8);
    }
    {
        const int node = node0 + (t >> 1);
        if (node < NN) {
            const float dv = ld[t >> 1];
            uint4* p = (uint4*)(A + (long)node * 16 + (t & 1) * 8);
            uint4 q = *p;
            q.x = sc2(q.x, dv); q.y = sc2(q.y, dv);
            q.z = sc2(q.z, dv); q.w = sc2(q.w, dv);
            *p = q;
        }
    }
}

// ---------------- pull-gather, 16 ch fp16 (persistent): B = dinv*relu(dg*(sum A)+b1) ----
__global__ __launch_bounds__(256) void gather16h_k(const int* __restrict__ rowptr,
                                                   const int* __restrict__ csr_src,
                                                   const float* __restrict__ dinv,
                                                   const __half* __restrict__ hs,
                                                   const float* __restrict__ bias,
                                                   __half* __restrict__ outp, int n) {
    const int lane = threadIdx.x & 63;
    const int wid0 = blockIdx.x * 4 + (threadIdx.x >> 6);
    const int nWaves = gridDim.x * 4;
    const int q = lane & 3;                 // uint2 chunk within 16-ch row
    const int sub = lane >> 2;              // edge subgroup 0..15
    const uint2* h2p = (const uint2*)hs;
    const float4 b = ((const float4*)bias)[q];
    for (int g = wid0; g < n; g += nWaves) {
        const float dg = dinv[g];
        const int beg = rowptr[g], end = rowptr[g + 1];
        float a0 = 0.f, a1 = 0.f, a2 = 0.f, a3 = 0.f;
        if (sub == 0) {                      // self term
            uint2 v = h2p[(long)g * 4 + q];
            h2acc(v.x, a0, a1); h2acc(v.y, a2, a3);
        }
        for (int j0 = beg; j0 < end; j0 += 16) {
            int idx = j0 + sub;
            if (idx < end) {
                const int s = csr_src[idx];
                uint2 v = h2p[(long)s * 4 + q];
                h2acc(v.x, a0, a1); h2acc(v.y, a2, a3);
            }
        }
#pragma unroll
        for (int m = 4; m <= 32; m <<= 1) {
            a0 += __shfl_xor(a0, m, 64);
            a1 += __shfl_xor(a1, m, 64);
            a2 += __shfl_xor(a2, m, 64);
            a3 += __shfl_xor(a3, m, 64);
        }
        if (sub == 0) {
            float v0 = fmaxf(fmaf(dg, a0, b.x), 0.0f) * dg;
            float v1 = fmaxf(fmaf(dg, a1, b.y), 0.0f) * dg;
            float v2 = fmaxf(fmaf(dg, a2, b.z), 0.0f) * dg;
            float v3 = fmaxf(fmaf(dg, a3, b.w), 0.0f) * dg;
            uint2 w;
            w.x = packh2(v0, v1);
            w.y = packh2(v2, v3);
            ((uint2*)outp)[(long)g * 4 + q] = w;
        }
    }
}

// ---------------- fused gather16 + gemm2: C = dinv*relu(dg*(sum B)@W2 + b2), fp16 out ----
__global__ __launch_bounds__(256) void g16gemm2h_k(const int* __restrict__ rowptr,
                                                   const int* __restrict__ csr_src,
                                                   const float* __restrict__ dinv,
                                                   const __half* __restrict__ hs,
                                                   const float* __restrict__ W2,
                                                   const float* __restrict__ b2,
                                                   __half* __restrict__ outp, int n) {
    const int lane = threadIdx.x & 63;
    const int wid = blockIdx.x * 4 + (threadIdx.x >> 6);
    const int nWaves = gridDim.x * 4;
    float w2[16];
#pragma unroll
    for (int k = 0; k < 16; ++k) w2[k] = W2[k * 64 + lane];
    const float bm = b2[lane];
    const int q = lane & 3;
    const int sub = lane >> 2;
    const uint2* h2p = (const uint2*)hs;
    for (int g = wid; g < n; g += nWaves) {
        const float dg = dinv[g];
        const int beg = rowptr[g], end = rowptr[g + 1];
        float a0 = 0.f, a1 = 0.f, a2 = 0.f, a3 = 0.f;
        if (sub == 0) {                      // self term
            uint2 v = h2p[(long)g * 4 + q];
            h2acc(v.x, a0, a1); h2acc(v.y, a2, a3);
        }
        for (int j0 = beg; j0 < end; j0 += 16) {
            int idx = j0 + sub;
            if (idx < end) {
                const int s = csr_src[idx];
                uint2 v = h2p[(long)s * 4 + q];
                h2acc(v.x, a0, a1); h2acc(v.y, a2, a3);
            }
        }
#pragma unroll
        for (int m = 4; m <= 32; m <<= 1) {
            a0 += __shfl_xor(a0, m, 64);
            a1 += __shfl_xor(a1, m, 64);
            a2 += __shfl_xor(a2, m, 64);
            a3 += __shfl_xor(a3, m, 64);
        }
        float t = 0.0f;
#pragma unroll
        for (int ql = 0; ql < 4; ++ql) {
            t = fmaf(rdl_f(a0, ql), w2[4 * ql + 0], t);
            t = fmaf(rdl_f(a1, ql), w2[4 * ql + 1], t);
            t = fmaf(rdl_f(a2, ql), w2[4 * ql + 2], t);
            t = fmaf(rdl_f(a3, ql), w2[4 * ql + 3], t);
        }
        float r = fmaxf(fmaf(dg, t, bm), 0.0f);   // dg*(sum)@W2 + b2, relu
        outp[(long)g * 64 + lane] = __float2half(r * dg);  // pre-scaled fp16
    }
}

// ---------------- pull-gather, 64 ch fp16 (R16 exact): agg = dg * sum C ----------------
__global__ __launch_bounds__(256) void gather64h_k(const int* __restrict__ rowptr,
                                                   const int* __restrict__ csr_src,
                                                   const float* __restrict__ dinv,
                                                   const __half* __restrict__ hs,
                                                   __half* __restrict__ outp, int n) {
    const int g = (blockIdx.x * 256 + threadIdx.x) >> 6;
    if (g >= n) return;
    const int lane = threadIdx.x & 63;
    const int q = lane & 7;                 // uint4 chunk within 64-ch row
    const int sub = lane >> 3;              // edge subgroup 0..7
    const float dg = dinv[g];
    const int beg = rowptr[g], end = rowptr[g + 1];
    const uint4* h4 = (const uint4*)hs;     // row = 8 chunks of 16B
    float a[8];
#pragma unroll
    for (int i = 0; i < 8; ++i) a[i] = 0.f;
    if (sub == 0) {                          // self term
        uint4 v = h4[(long)g * 8 + q];
        h2acc(v.x, a[0], a[1]); h2acc(v.y, a[2], a[3]);
        h2acc(v.z, a[4], a[5]); h2acc(v.w, a[6], a[7]);
    }
    int j0 = beg;
    for (; j0 + 16 <= end; j0 += 16) {
        const int s0 = csr_src[j0 + sub];
        const int s1 = csr_src[j0 + 8 + sub];
        const uint4 v0 = h4[(long)s0 * 8 + q];
        const uint4 v1 = h4[(long)s1 * 8 + q];
        h2acc(v0.x, a[0], a[1]); h2acc(v0.y, a[2], a[3]);
        h2acc(v0.z, a[4], a[5]); h2acc(v0.w, a[6], a[7]);
        h2acc(v1.x, a[0], a[1]); h2acc(v1.y, a[2], a[3]);
        h2acc(v1.z, a[4], a[5]); h2acc(v1.w, a[6], a[7]);
    }
    for (; j0 < end; j0 += 8) {
        int idx = j0 + sub;
        if (idx < end) {
            const int s = csr_src[idx];
            const uint4 v = h4[(long)s * 8 + q];
            h2acc(v.x, a[0], a[1]); h2acc(v.y, a[2], a[3]);
            h2acc(v.z, a[4], a[5]); h2acc(v.w, a[6], a[7]);
        }
    }
#pragma unroll
    for (int m = 8; m <= 32; m <<= 1) {
#pragma unroll
        for (int i = 0; i < 8; ++i) a[i] += __shfl_xor(a[i], m, 64);
    }
    if (sub == 0) {
        uint4 w;
        w.x = packh2(a[0] * dg, a[1] * dg);
        w.y = packh2(a[2] * dg, a[3] * dg);
        w.z = packh2(a[4] * dg, a[5] * dg);
        w.w = packh2(a[6] * dg, a[7] * dg);
        ((uint4*)outp)[(long)g * 8 + q] = w;
    }
}

// ---------------- MFMA head: out = relu(agg@W3 + b3).Wfc + bfc ----------------
__global__ __launch_bounds__(256) void head_mfma_k(const __half* __restrict__ agg,
                                                   const float* __restrict__ W3,
                                                   const float* __restrict__ b3,
                                                   const float* __restrict__ Wfc,
                                                   const float* __restrict__ bfc,
                                                   float* __restrict__ out, int n) {
    __shared__ _Float16 sWf[8192];           // 16 KB, frag-layout
    const int tid = threadIdx.x;
    for (int i = tid; i < 8192; i += 256) {
        const int j = i & 7;
        const int l = (i >> 3) & 63;
        const int th = i >> 9;
        const int k = (th & 1) * 32 + ((l >> 4) << 3) + j;
        const int nn = (th >> 1) * 16 + (l & 15);
        sWf[i] = (_Float16)W3[k * 128 + nn];
    }
    __syncthreads();
    const int lane = tid & 63;
    const int wid = blockIdx.x * 4 + (tid >> 6);
    const int nWaves = gridDim.x * 4;
    const int col = lane & 15;
    const int kg = lane >> 4;
    half8 wf[16];
#pragma unroll
    for (int q2 = 0; q2 < 16; ++q2)
        wf[q2] = *((const half8*)&sWf[(q2 * 64 + lane) * 8]);
    float b3v[8], wfv[8];
#pragma unroll
    for (int t = 0; t < 8; ++t) {
        b3v[t] = b3[t * 16 + col];
        wfv[t] = Wfc[t * 16 + col];
    }
    const float bb = bfc[0];
    const int nTiles = n >> 4;               // 6250, exact
    union { uint4 u; half8 h; } cva, cvb;
    for (int tile = wid; tile < nTiles; tile += nWaves) {
        const int node0 = tile << 4;
        const uint4* rowp = (const uint4*)(agg + (long)(node0 + col) * 64);
        cva.u = rowp[kg];                     // k = kg*8 .. +8   (half 0)
        cvb.u = rowp[4 + kg];                 // k = 32 + kg*8..  (half 1)
        const half8 a0 = cva.h, a1 = cvb.h;
        f32x4 c[8];
#pragma unroll
        for (int t = 0; t < 8; ++t) {
            f32x4 z = {0.f, 0.f, 0.f, 0.f};
            c[t] = __builtin_amdgcn_mfma_f32_16x16x32_f16(a0, wf[t * 2], z, 0, 0, 0);
            c[t] = __builtin_amdgcn_mfma_f32_16x16x32_f16(a1, wf[t * 2 + 1], c[t], 0, 0, 0);
        }
        float s0 = 0.f, s1 = 0.f, s2 = 0.f, s3 = 0.f;
#pragma unroll
        for (int t = 0; t < 8; ++t) {
            s0 += fmaxf(c[t][0] + b3v[t], 0.f) * wfv[t];
            s1 += fmaxf(c[t][1] + b3v[t], 0.f) * wfv[t];
            s2 += fmaxf(c[t][2] + b3v[t], 0.f) * wfv[t];
            s3 += fmaxf(c[t][3] + b3v[t], 0.f) * wfv[t];
        }
#pragma unroll
        for (int m = 1; m <= 8; m <<= 1) {
            s0 += __shfl_xor(s0, m, 64);
            s1 += __shfl_xor(s1, m, 64);
            s2 += __shfl_xor(s2, m, 64);
            s3 += __shfl_xor(s3, m, 64);
        }
        if (col == 0) {
            const int nb = node0 + kg * 4;
            out[nb]     = s0 + bb;
            out[nb + 1] = s1 + bb;
            out[nb + 2] = s2 + bb;
            out[nb + 3] = s3 + bb;
        }
    }
}

extern "C" void kernel_launch(void* const* d_in, const int* in_sizes, int n_in,
                              void* d_out, int out_size, void* d_ws, size_t ws_size,
                              hipStream_t stream) {
    const float* x    = (const float*)d_in[0];
    const int*   ei   = (const int*)d_in[1];       // [2,E]: src = ei, dst = ei+E
    const float* W1   = (const float*)d_in[2];
    const float* b1   = (const float*)d_in[3];
    const float* W2   = (const float*)d_in[4];
    const float* b2   = (const float*)d_in[5];
    const float* W3   = (const float*)d_in[6];
    const float* b3   = (const float*)d_in[7];
    const float* Wfc  = (const float*)d_in[8];
    const float* bfc  = (const float*)d_in[9];
    float* out = (float*)d_out;

    const int* src = ei;
    const int* dst = ei + NE;

    // workspace layout (16B-aligned offsets; 4B units):
    // dinv[N] | rowptr[N+8] | mat[NBLK*NB2] | ofsT[NBLK*NB2] | colTotal[512]
    // | bucketBase[512] | csr_src[E+64] | bucketed[E] u32
    // | A_h[16N] fp16 | B_h[16N] fp16 | C_h[64N] fp16 | agg_h[64N] fp16
    float* dinv        = (float*)d_ws;
    int*   rowptr      = (int*)(dinv + NN);
    int*   mat         = rowptr + NN + 8;
    int*   ofsT        = mat + NBLK * NB2 + 4;
    int*   colTotal    = ofsT + NBLK * NB2 + 4;
    int*   bucketBase  = colTotal + 512;
    int*   csr_src     = bucketBase + 512;
    unsigned* bucketed = (unsigned*)(csr_src + NE + 64);
    __half* A_h        = (__half*)(bucketed + NE);
    __half* B_h        = A_h + (long)NN * 16;
    __half* C_h        = B_h + (long)NN * 16;
    __half* agg_h      = C_h + (long)NN * 64;

    const int T = 256;

    // ---- CSR build (atomic-free) + MFMA gemm1 overlapped ----
    const int gemmBlocks = (NN + 63) / 64;             // 1563
    count_gemm1_k<<<NBLK + gemmBlocks, T, 0, stream>>>(dst, mat, x, W1, A_h, NN);
    colscan_k<<<NB2, 64, 0, stream>>>(mat, ofsT, colTotal);
    p2_scatter_k<<<NBLK, 512, 0, stream>>>(src, dst, ofsT, colTotal, bucketBase, bucketed);
    p3_csr_k<<<NB2, 512, 0, stream>>>(bucketed, bucketBase, rowptr, dinv, csr_src, A_h);

    // ---- B = dinv * relu(dg*(sum A) + b1)  (pre-scaled r1, 16ch fp16) ----
    gather16h_k<<<3072, T, 0, stream>>>(rowptr, csr_src, dinv, A_h, b1, B_h, NN);
    // ---- C = dinv * relu(dg*(sum B)@W2 + b2)  (pre-scaled r2, 64ch fp16) ----
    g16gemm2h_k<<<3072, T, 0, stream>>>(rowptr, csr_src, dinv, B_h, W2, b2, C_h, NN);
    // ---- agg(64ch fp16) = dg * sum C ----
    gather64h_k<<<(NN + 3) / 4, T, 0, stream>>>(rowptr, csr_src, dinv, C_h, agg_h, NN);
    // ---- head: out = relu(agg@W3 + b3).Wfc + bfc  (MFMA) ----
    head_mfma_k<<<256, T, 0, stream>>>(agg_h, W3, b3, Wfc, bfc, out, NN);
}

// Round 9
// 260.226 us; speedup vs baseline: 1.4314x; 1.0214x over previous
//
#include <hip/hip_runtime.h>
#include <hip/hip_fp16.h>

// GCN: N=100000, E=1600000, widths 128 -> 16 -> 64 -> 128 -> 1
// Round 20 (from 265.8us R19):
//  POST-MORTEM R19: gemm1->MFMA only bought ~3us -- count_gemm1 is dominated
//  by the histogram half + x-read BW, not MACs. gather64h is at its ~3.5TB/s
//  L2-miss structural floor. Remaining time is spread across the CSR build.
//  This round, safe modeled cuts there:
//  (1) p3: stage bucket edges in LDS (one coalesced read vs two global
//      passes), hist+scatter in LDS, coalesced csr window flush. Cap 5120
//      edges/bucket (+16 sigma; global-path fallback kept).
//  (2) p2 + count hist: int4 edge loads (4 edges/instr; offsets 16B-aligned,
//      tails 4-divisible).
//  All else frozen: gather64h R16-exact, MFMA head/gemm1, persistent g16s.
// Pipeline: count+gemm1(MFMA) -> colscan -> p2 -> p3
//           -> gather16(r1) -> g16gemm2(r2) -> gather64 -> head(MFMA).

#define NN 100000
#define NE 1600000
#define SHIFT 8                      // 256 nodes per bucket
#define NB2 391                      // ceil(NN/256)
#define EPB 4096                     // edges per P1/P2 block
#define NBLK 391                     // ceil(NE/EPB)
#define CHUNK 7                      // ceil(NBLK/64) for colscan
#define BCAP 5120                    // LDS bucket capacity in p3 (mean 4096, sd 64)

typedef _Float16 half8 __attribute__((ext_vector_type(8)));
typedef float f32x4 __attribute__((ext_vector_type(4)));

__device__ __forceinline__ float rdl_f(float v, int l) {
    return __int_as_float(__builtin_amdgcn_readlane(__float_as_int(v), l));
}

// unpack one half2 word, accumulate into two fp32 lanes
__device__ __forceinline__ void h2acc(unsigned u, float& a, float& b) {
    __half2 h = *reinterpret_cast<__half2*>(&u);
    float2 f = __half22float2(h);
    a += f.x; b += f.y;
}
__device__ __forceinline__ unsigned packh2(float a, float b) {
    __half2 h = __floats2half2_rn(a, b);
    return *reinterpret_cast<unsigned*>(&h);
}
__device__ __forceinline__ unsigned sc2(unsigned u, float s) {
    __half2 h = *reinterpret_cast<__half2*>(&u);
    float2 f = __half22float2(h);
    return packh2(f.x * s, f.y * s);
}

// ---------------- P1: bucket counts (blocks < NBLK) + MFMA gemm1 (rest) ----------------
// gemm1_raw: A = x @ W1 (unscaled; dinv applied in P3), K=128, M=16, fp16 out.
__global__ __launch_bounds__(256) void count_gemm1_k(const int* __restrict__ dst,
                                                     int* __restrict__ mat,
                                                     const float* __restrict__ x,
                                                     const float* __restrict__ W1,
                                                     __half* __restrict__ A, int n) {
    __shared__ int cnt[NB2];
    __shared__ _Float16 sW1f[2048];          // 4 k-tiles x 64 lanes x 8 (frag layout)
    __shared__ unsigned sxu[4][16][68];      // per-wave fp16 x-tile, 136-half rows
    const int tid = threadIdx.x;
    if ((int)blockIdx.x < NBLK) {
        for (int i = tid; i < NB2; i += 256) cnt[i] = 0;
        __syncthreads();
        const int e0 = blockIdx.x * EPB;
        const int e1 = min(e0 + EPB, NE);
        int i = e0 + tid * 4;
        for (; i + 3 < e1; i += 1024) {
            const int4 d4 = *(const int4*)&dst[i];
            atomicAdd(&cnt[d4.x >> SHIFT], 1);
            atomicAdd(&cnt[d4.y >> SHIFT], 1);
            atomicAdd(&cnt[d4.z >> SHIFT], 1);
            atomicAdd(&cnt[d4.w >> SHIFT], 1);
        }
        for (; i < e1; ++i) atomicAdd(&cnt[dst[i] >> SHIFT], 1);
        __syncthreads();
        for (int c = tid; c < NB2; c += 256) mat[blockIdx.x * NB2 + c] = cnt[c];
        return;
    }
    const int bid = blockIdx.x - NBLK;
    const int row0 = bid * 64;
    for (int i = tid; i < 2048; i += 256) {
        const int kt = i >> 9;
        const int l = (i >> 3) & 63;
        const int j = i & 7;
        const int k = kt * 32 + ((l >> 4) << 3) + j;
        sW1f[i] = (_Float16)W1[k * 16 + (l & 15)];
    }
    const float4* in4 = (const float4*)x;
    for (int i = tid; i < 2048; i += 256) {
        const int r = i >> 5, kv = i & 31;
        const int g = row0 + r;
        float4 v = make_float4(0.f, 0.f, 0.f, 0.f);
        if (g < n) v = in4[(long)g * 32 + kv];
        unsigned* su = &sxu[r >> 4][r & 15][0];
        su[kv * 2]     = packh2(v.x, v.y);
        su[kv * 2 + 1] = packh2(v.z, v.w);
    }
    __syncthreads();
    const int w = tid >> 6, l = tid & 63;
    const int node0 = row0 + w * 16;
    f32x4 c = {0.f, 0.f, 0.f, 0.f};
#pragma unroll
    for (int kt = 0; kt < 4; ++kt) {
        const half8 a = *(const half8*)&sxu[w][l & 15][kt * 16 + ((l >> 4) << 2)];
        const half8 b = *(const half8*)&sW1f[kt * 512 + l * 8];
        c = __builtin_amdgcn_mfma_f32_16x16x32_f16(a, b, c, 0, 0, 0);
    }
#pragma unroll
    for (int i = 0; i < 4; ++i) {
        const int g = node0 + ((l >> 4) << 2) + i;
        if (g < n) A[(long)g * 16 + (l & 15)] = __float2half(c[i]);
    }
}

// ---------------- colscan: per-bucket exclusive scan over edge-blocks ----------------
__global__ __launch_bounds__(64) void colscan_k(const int* __restrict__ mat,
                                                int* __restrict__ ofsT,
                                                int* __restrict__ colTotal) {
    const int c = blockIdx.x;
    const int lane = threadIdx.x;
    int v[CHUNK];
    int s = 0;
    const int base = lane * CHUNK;
#pragma unroll
    for (int j = 0; j < CHUNK; ++j) {
        int b = base + j;
        int x_ = (b < NBLK) ? mat[b * NB2 + c] : 0;
        v[j] = s;              // local exclusive prefix
        s += x_;
    }
    int inc = s;
#pragma unroll
    for (int d = 1; d < 64; d <<= 1) {
        int t = __shfl_up(inc, d, 64);
        if (lane >= d) inc += t;
    }
    const int excl = inc - s;
#pragma unroll
    for (int j = 0; j < CHUNK; ++j) {
        int b = base + j;
        if (b < NBLK) ofsT[b * NB2 + c] = excl + v[j];
    }
    if (lane == 63) colTotal[c] = excl + s;
}

// ---------------- P2: scatter packed edges; block 0 publishes bucketBase -------------
__global__ __launch_bounds__(512) void p2_scatter_k(const int* __restrict__ src,
                                                    const int* __restrict__ dst,
                                                    const int* __restrict__ ofsT,
                                                    const int* __restrict__ colTotal,
                                                    int* __restrict__ bucketBase,
                                                    unsigned* __restrict__ bucketed) {
    __shared__ int sc[512];
    __shared__ int cur[NB2];
    const int b = blockIdx.x;
    const int t = threadIdx.x;
    int v = (t < NB2) ? colTotal[t] : 0;
    sc[t] = v;
    __syncthreads();
    for (int off = 1; off < 512; off <<= 1) {
        int a = (t >= off) ? sc[t - off] : 0;
        __syncthreads();
        sc[t] += a;
        __syncthreads();
    }
    if (t < NB2) cur[t] = (sc[t] - v) + ofsT[b * NB2 + t];
    if (b == 0) {
        if (t < NB2) bucketBase[t] = sc[t] - v;
        if (t == NB2) bucketBase[NB2] = NE;
    }
    __syncthreads();
    const int e0 = b * EPB;
    const int e1 = min(e0 + EPB, NE);
    int i = e0 + t * 4;
    const int stride = 512 * 4;
    for (; i + 3 < e1; i += stride) {
        const int4 d4 = *(const int4*)&dst[i];
        const int4 s4 = *(const int4*)&src[i];
        const int p0 = atomicAdd(&cur[d4.x >> SHIFT], 1);
        const int p1 = atomicAdd(&cur[d4.y >> SHIFT], 1);
        const int p2 = atomicAdd(&cur[d4.z >> SHIFT], 1);
        const int p3 = atomicAdd(&cur[d4.w >> SHIFT], 1);
        bucketed[p0] = ((unsigned)s4.x << 8) | (unsigned)(d4.x & 255);
        bucketed[p1] = ((unsigned)s4.y << 8) | (unsigned)(d4.y & 255);
        bucketed[p2] = ((unsigned)s4.z << 8) | (unsigned)(d4.z & 255);
        bucketed[p3] = ((unsigned)s4.w << 8) | (unsigned)(d4.w & 255);
    }
    for (; i < e1; ++i) {
        const int d = dst[i];
        const int pos = atomicAdd(&cur[d >> SHIFT], 1);
        bucketed[pos] = ((unsigned)src[i] << 8) | (unsigned)(d & 255);
    }
}

// ---------------- P3: per-bucket CSR via LDS staging + A rescale ----------------
__global__ __launch_bounds__(512) void p3_csr_k(const unsigned* __restrict__ bucketed,
                                                const int* __restrict__ bucketBase,
                                                int* __restrict__ rowptr,
                                                float* __restrict__ dinv,
                                                int* __restrict__ csr_src,
                                                __half* __restrict__ A) {
    __shared__ unsigned sEdge[BCAP];
    __shared__ int sCsr[BCAP];
    __shared__ int cnt[256];
    __shared__ int excl[256];
    __shared__ float ld[256];
    const int c = blockIdx.x;
    const int t = threadIdx.x;
    const int base = bucketBase[c];
    const int end  = bucketBase[c + 1];
    const int sz = end - base;
    if (t < 256) cnt[t] = 0;
    const bool inLds = (sz <= BCAP);
    if (inLds) {
        for (int i = t; i < sz; i += 512) sEdge[i] = bucketed[base + i];
    }
    __syncthreads();
    // phase A: histogram
    if (inLds) {
        for (int i = t; i < sz; i += 512) atomicAdd(&cnt[sEdge[i] & 255u], 1);
    } else {
        for (int i = base + t; i < end; i += 512) atomicAdd(&cnt[bucketed[i] & 255u], 1);
    }
    __syncthreads();
    // phase B: inclusive scan of 256 counts (guarded for 512 threads)
    if (t < 256) excl[t] = cnt[t];
    __syncthreads();
    for (int off = 1; off < 256; off <<= 1) {
        int a = (t < 256 && t >= off) ? excl[t - off] : 0;
        __syncthreads();
        if (t < 256) excl[t] += a;
        __syncthreads();
    }
    const int node0 = c << SHIFT;
    if (t < 256) {
        const int node = node0 + t;
        const int ex = excl[t] - cnt[t];
        if (node < NN) {
            rowptr[node] = base + ex;
            const float dv = rsqrtf((float)cnt[t] + 1.0f);  // +1 self loop
            dinv[node] = dv;
            ld[t] = dv;
        }
        excl[t] = ex;  // becomes the fill cursor
    }
    if (c == NB2 - 1 && t == 0) rowptr[NN] = NE;
    __syncthreads();
    // phase C: scatter into csr window
    if (inLds) {
        for (int i = t; i < sz; i += 512) {
            const unsigned p = sEdge[i];
            const int pos = atomicAdd(&excl[p & 255u], 1);
            sCsr[pos] = (int)(p >> 8);
        }
        __syncthreads();
        for (int i = t; i < sz; i += 512) csr_src[base + i] = sCsr[i];
    } else {
        for (int i = base + t; i < end; i += 512) {
            const unsigned p = bucketed[i];
            const int pos = atomicAdd(&excl[p & 255u], 1);
            csr_src[base + pos] = (int)(p >> 8);
        }
    }
    // phase D: rescale A rows by dinv (2 threads per node)
    {
        const int node = node0 + (t >> 1);
        if (node < NN) {
            const float dv = ld[t >> 1];
            uint4* p = (uint4*)(A + (long)node * 16 + (t & 1) * 8);
            uint4 q = *p;
            q.x = sc2(q.x, dv); q.y = sc2(q.y, dv);
            q.z = sc2(q.z, dv); q.w = sc2(q.w, dv);
            *p = q;
        }
    }
}

// ---------------- pull-gather, 16 ch fp16 (persistent): B = dinv*relu(dg*(sum A)+b1) ----
__global__ __launch_bounds__(256) void gather16h_k(const int* __restrict__ rowptr,
                                                   const int* __restrict__ csr_src,
                                                   const float* __restrict__ dinv,
                                                   const __half* __restrict__ hs,
                                                   const float* __restrict__ bias,
                                                   __half* __restrict__ outp, int n) {
    const int lane = threadIdx.x & 63;
    const int wid0 = blockIdx.x * 4 + (threadIdx.x >> 6);
    const int nWaves = gridDim.x * 4;
    const int q = lane & 3;                 // uint2 chunk within 16-ch row
    const int sub = lane >> 2;              // edge subgroup 0..15
    const uint2* h2p = (const uint2*)hs;
    const float4 b = ((const float4*)bias)[q];
    for (int g = wid0; g < n; g += nWaves) {
        const float dg = dinv[g];
        const int beg = rowptr[g], end = rowptr[g + 1];
        float a0 = 0.f, a1 = 0.f, a2 = 0.f, a3 = 0.f;
        if (sub == 0) {                      // self term
            uint2 v = h2p[(long)g * 4 + q];
            h2acc(v.x, a0, a1); h2acc(v.y, a2, a3);
        }
        for (int j0 = beg; j0 < end; j0 += 16) {
            int idx = j0 + sub;
            if (idx < end) {
                const int s = csr_src[idx];
                uint2 v = h2p[(long)s * 4 + q];
                h2acc(v.x, a0, a1); h2acc(v.y, a2, a3);
            }
        }
#pragma unroll
        for (int m = 4; m <= 32; m <<= 1) {
            a0 += __shfl_xor(a0, m, 64);
            a1 += __shfl_xor(a1, m, 64);
            a2 += __shfl_xor(a2, m, 64);
            a3 += __shfl_xor(a3, m, 64);
        }
        if (sub == 0) {
            float v0 = fmaxf(fmaf(dg, a0, b.x), 0.0f) * dg;
            float v1 = fmaxf(fmaf(dg, a1, b.y), 0.0f) * dg;
            float v2 = fmaxf(fmaf(dg, a2, b.z), 0.0f) * dg;
            float v3 = fmaxf(fmaf(dg, a3, b.w), 0.0f) * dg;
            uint2 w;
            w.x = packh2(v0, v1);
            w.y = packh2(v2, v3);
            ((uint2*)outp)[(long)g * 4 + q] = w;
        }
    }
}

// ---------------- fused gather16 + gemm2: C = dinv*relu(dg*(sum B)@W2 + b2), fp16 out ----
__global__ __launch_bounds__(256) void g16gemm2h_k(const int* __restrict__ rowptr,
                                                   const int* __restrict__ csr_src,
                                                   const float* __restrict__ dinv,
                                                   const __half* __restrict__ hs,
                                                   const float* __restrict__ W2,
                                                   const float* __restrict__ b2,
                                                   __half* __restrict__ outp, int n) {
    const int lane = threadIdx.x & 63;
    const int wid = blockIdx.x * 4 + (threadIdx.x >> 6);
    const int nWaves = gridDim.x * 4;
    float w2[16];
#pragma unroll
    for (int k = 0; k < 16; ++k) w2[k] = W2[k * 64 + lane];
    const float bm = b2[lane];
    const int q = lane & 3;
    const int sub = lane >> 2;
    const uint2* h2p = (const uint2*)hs;
    for (int g = wid; g < n; g += nWaves) {
        const float dg = dinv[g];
        const int beg = rowptr[g], end = rowptr[g + 1];
        float a0 = 0.f, a1 = 0.f, a2 = 0.f, a3 = 0.f;
        if (sub == 0) {                      // self term
            uint2 v = h2p[(long)g * 4 + q];
            h2acc(v.x, a0, a1); h2acc(v.y, a2, a3);
        }
        for (int j0 = beg; j0 < end; j0 += 16) {
            int idx = j0 + sub;
            if (idx < end) {
                const int s = csr_src[idx];
                uint2 v = h2p[(long)s * 4 + q];
                h2acc(v.x, a0, a1); h2acc(v.y, a2, a3);
            }
        }
#pragma unroll
        for (int m = 4; m <= 32; m <<= 1) {
            a0 += __shfl_xor(a0, m, 64);
            a1 += __shfl_xor(a1, m, 64);
            a2 += __shfl_xor(a2, m, 64);
            a3 += __shfl_xor(a3, m, 64);
        }
        float t = 0.0f;
#pragma unroll
        for (int ql = 0; ql < 4; ++ql) {
            t = fmaf(rdl_f(a0, ql), w2[4 * ql + 0], t);
            t = fmaf(rdl_f(a1, ql), w2[4 * ql + 1], t);
            t = fmaf(rdl_f(a2, ql), w2[4 * ql + 2], t);
            t = fmaf(rdl_f(a3, ql), w2[4 * ql + 3], t);
        }
        float r = fmaxf(fmaf(dg, t, bm), 0.0f);   // dg*(sum)@W2 + b2, relu
        outp[(long)g * 64 + lane] = __float2half(r * dg);  // pre-scaled fp16
    }
}

// ---------------- pull-gather, 64 ch fp16 (R16 exact): agg = dg * sum C ----------------
__global__ __launch_bounds__(256) void gather64h_k(const int* __restrict__ rowptr,
                                                   const int* __restrict__ csr_src,
                                                   const float* __restrict__ dinv,
                                                   const __half* __restrict__ hs,
                                                   __half* __restrict__ outp, int n) {
    const int g = (blockIdx.x * 256 + threadIdx.x) >> 6;
    if (g >= n) return;
    const int lane = threadIdx.x & 63;
    const int q = lane & 7;                 // uint4 chunk within 64-ch row
    const int sub = lane >> 3;              // edge subgroup 0..7
    const float dg = dinv[g];
    const int beg = rowptr[g], end = rowptr[g + 1];
    const uint4* h4 = (const uint4*)hs;     // row = 8 chunks of 16B
    float a[8];
#pragma unroll
    for (int i = 0; i < 8; ++i) a[i] = 0.f;
    if (sub == 0) {                          // self term
        uint4 v = h4[(long)g * 8 + q];
        h2acc(v.x, a[0], a[1]); h2acc(v.y, a[2], a[3]);
        h2acc(v.z, a[4], a[5]); h2acc(v.w, a[6], a[7]);
    }
    int j0 = beg;
    for (; j0 + 16 <= end; j0 += 16) {
        const int s0 = csr_src[j0 + sub];
        const int s1 = csr_src[j0 + 8 + sub];
        const uint4 v0 = h4[(long)s0 * 8 + q];
        const uint4 v1 = h4[(long)s1 * 8 + q];
        h2acc(v0.x, a[0], a[1]); h2acc(v0.y, a[2], a[3]);
        h2acc(v0.z, a[4], a[5]); h2acc(v0.w, a[6], a[7]);
        h2acc(v1.x, a[0], a[1]); h2acc(v1.y, a[2], a[3]);
        h2acc(v1.z, a[4], a[5]); h2acc(v1.w, a[6], a[7]);
    }
    for (; j0 < end; j0 += 8) {
        int idx = j0 + sub;
        if (idx < end) {
            const int s = csr_src[idx];
            const uint4 v = h4[(long)s * 8 + q];
            h2acc(v.x, a[0], a[1]); h2acc(v.y, a[2], a[3]);
            h2acc(v.z, a[4], a[5]); h2acc(v.w, a[6], a[7]);
        }
    }
#pragma unroll
    for (int m = 8; m <= 32; m <<= 1) {
#pragma unroll
        for (int i = 0; i < 8; ++i) a[i] += __shfl_xor(a[i], m, 64);
    }
    if (sub == 0) {
        uint4 w;
        w.x = packh2(a[0] * dg, a[1] * dg);
        w.y = packh2(a[2] * dg, a[3] * dg);
        w.z = packh2(a[4] * dg, a[5] * dg);
        w.w = packh2(a[6] * dg, a[7] * dg);
        ((uint4*)outp)[(long)g * 8 + q] = w;
    }
}

// ---------------- MFMA head: out = relu(agg@W3 + b3).Wfc + bfc ----------------
__global__ __launch_bounds__(256) void head_mfma_k(const __half* __restrict__ agg,
                                                   const float* __restrict__ W3,
                                                   const float* __restrict__ b3,
                                                   const float* __restrict__ Wfc,
                                                   const float* __restrict__ bfc,
                                                   float* __restrict__ out, int n) {
    __shared__ _Float16 sWf[8192];           // 16 KB, frag-layout
    const int tid = threadIdx.x;
    for (int i = tid; i < 8192; i += 256) {
        const int j = i & 7;
        const int l = (i >> 3) & 63;
        const int th = i >> 9;
        const int k = (th & 1) * 32 + ((l >> 4) << 3) + j;
        const int nn = (th >> 1) * 16 + (l & 15);
        sWf[i] = (_Float16)W3[k * 128 + nn];
    }
    __syncthreads();
    const int lane = tid & 63;
    const int wid = blockIdx.x * 4 + (tid >> 6);
    const int nWaves = gridDim.x * 4;
    const int col = lane & 15;
    const int kg = lane >> 4;
    half8 wf[16];
#pragma unroll
    for (int q2 = 0; q2 < 16; ++q2)
        wf[q2] = *((const half8*)&sWf[(q2 * 64 + lane) * 8]);
    float b3v[8], wfv[8];
#pragma unroll
    for (int t = 0; t < 8; ++t) {
        b3v[t] = b3[t * 16 + col];
        wfv[t] = Wfc[t * 16 + col];
    }
    const float bb = bfc[0];
    const int nTiles = n >> 4;               // 6250, exact
    union { uint4 u; half8 h; } cva, cvb;
    for (int tile = wid; tile < nTiles; tile += nWaves) {
        const int node0 = tile << 4;
        const uint4* rowp = (const uint4*)(agg + (long)(node0 + col) * 64);
        cva.u = rowp[kg];                     // k = kg*8 .. +8   (half 0)
        cvb.u = rowp[4 + kg];                 // k = 32 + kg*8..  (half 1)
        const half8 a0 = cva.h, a1 = cvb.h;
        f32x4 c[8];
#pragma unroll
        for (int t = 0; t < 8; ++t) {
            f32x4 z = {0.f, 0.f, 0.f, 0.f};
            c[t] = __builtin_amdgcn_mfma_f32_16x16x32_f16(a0, wf[t * 2], z, 0, 0, 0);
            c[t] = __builtin_amdgcn_mfma_f32_16x16x32_f16(a1, wf[t * 2 + 1], c[t], 0, 0, 0);
        }
        float s0 = 0.f, s1 = 0.f, s2 = 0.f, s3 = 0.f;
#pragma unroll
        for (int t = 0; t < 8; ++t) {
            s0 += fmaxf(c[t][0] + b3v[t], 0.f) * wfv[t];
            s1 += fmaxf(c[t][1] + b3v[t], 0.f) * wfv[t];
            s2 += fmaxf(c[t][2] + b3v[t], 0.f) * wfv[t];
            s3 += fmaxf(c[t][3] + b3v[t], 0.f) * wfv[t];
        }
#pragma unroll
        for (int m = 1; m <= 8; m <<= 1) {
            s0 += __shfl_xor(s0, m, 64);
            s1 += __shfl_xor(s1, m, 64);
            s2 += __shfl_xor(s2, m, 64);
            s3 += __shfl_xor(s3, m, 64);
        }
        if (col == 0) {
            const int nb = node0 + kg * 4;
            out[nb]     = s0 + bb;
            out[nb + 1] = s1 + bb;
            out[nb + 2] = s2 + bb;
            out[nb + 3] = s3 + bb;
        }
    }
}

extern "C" void kernel_launch(void* const* d_in, const int* in_sizes, int n_in,
                              void* d_out, int out_size, void* d_ws, size_t ws_size,
                              hipStream_t stream) {
    const float* x    = (const float*)d_in[0];
    const int*   ei   = (const int*)d_in[1];       // [2,E]: src = ei, dst = ei+E
    const float* W1   = (const float*)d_in[2];
    const float* b1   = (const float*)d_in[3];
    const float* W2   = (const float*)d_in[4];
    const float* b2   = (const float*)d_in[5];
    const float* W3   = (const float*)d_in[6];
    const float* b3   = (const float*)d_in[7];
    const float* Wfc  = (const float*)d_in[8];
    const float* bfc  = (const float*)d_in[9];
    float* out = (float*)d_out;

    const int* src = ei;
    const int* dst = ei + NE;

    // workspace layout (16B-aligned offsets; 4B units):
    // dinv[N] | rowptr[N+8] | mat[NBLK*NB2] | ofsT[NBLK*NB2] | colTotal[512]
    // | bucketBase[512] | csr_src[E+64] | bucketed[E] u32
    // | A_h[16N] fp16 | B_h[16N] fp16 | C_h[64N] fp16 | agg_h[64N] fp16
    float* dinv        = (float*)d_ws;
    int*   rowptr      = (int*)(dinv + NN);
    int*   mat         = rowptr + NN + 8;
    int*   ofsT        = mat + NBLK * NB2 + 4;
    int*   colTotal    = ofsT + NBLK * NB2 + 4;
    int*   bucketBase  = colTotal + 512;
    int*   csr_src     = bucketBase + 512;
    unsigned* bucketed = (unsigned*)(csr_src + NE + 64);
    __half* A_h        = (__half*)(bucketed + NE);
    __half* B_h        = A_h + (long)NN * 16;
    __half* C_h        = B_h + (long)NN * 16;
    __half* agg_h      = C_h + (long)NN * 64;

    const int T = 256;

    // ---- CSR build (atomic-free) + MFMA gemm1 overlapped ----
    const int gemmBlocks = (NN + 63) / 64;             // 1563
    count_gemm1_k<<<NBLK + gemmBlocks, T, 0, stream>>>(dst, mat, x, W1, A_h, NN);
    colscan_k<<<NB2, 64, 0, stream>>>(mat, ofsT, colTotal);
    p2_scatter_k<<<NBLK, 512, 0, stream>>>(src, dst, ofsT, colTotal, bucketBase, bucketed);
    p3_csr_k<<<NB2, 512, 0, stream>>>(bucketed, bucketBase, rowptr, dinv, csr_src, A_h);

    // ---- B = dinv * relu(dg*(sum A) + b1)  (pre-scaled r1, 16ch fp16) ----
    gather16h_k<<<3072, T, 0, stream>>>(rowptr, csr_src, dinv, A_h, b1, B_h, NN);
    // ---- C = dinv * relu(dg*(sum B)@W2 + b2)  (pre-scaled r2, 64ch fp16) ----
    g16gemm2h_k<<<3072, T, 0, stream>>>(rowptr, csr_src, dinv, B_h, W2, b2, C_h, NN);
    // ---- agg(64ch fp16) = dg * sum C ----
    gather64h_k<<<(NN + 3) / 4, T, 0, stream>>>(rowptr, csr_src, dinv, C_h, agg_h, NN);
    // ---- head: out = relu(agg@W3 + b3).Wfc + bfc  (MFMA) ----
    head_mfma_k<<<256, T, 0, stream>>>(agg_h, W3, b3, Wfc, bfc, out, NN);
}

// Round 10
// 248.826 us; speedup vs baseline: 1.4970x; 1.0458x over previous
//
#include <hip/hip_runtime.h>
#include <hip/hip_fp16.h>

// GCN: N=100000, E=1600000, widths 128 -> 16 -> 64 -> 128 -> 1
// Round 21 (from 260.2us R20):
//  Blind-split-safe cuts only (top-5 shows only gather64h; middle split
//  unknown -- changes below have mechanisms independent of that split):
//  (1) gather16h/g16gemm2h grids 3072 -> 2048 blocks = exact resident
//      capacity (8 blk/CU x 256 CU) -> one balanced persistent pass, no
//      1.5-pass ragged tail (R17's gather64 lesson applied to the g16s).
//  (2) p2 scan: 512-wide Hillis-Steele (18 barriers) -> wave-shuffle hybrid
//      (6 shfl_up steps + 8-entry cross-wave LDS prefix, 1 barrier).
//  Frozen: gather64h R16-exact (at ~3.5TB/s L2-miss floor), MFMA gemm1/head,
//  p3 LDS staging, int4 edge loads.
// Pipeline: count+gemm1(MFMA) -> colscan -> p2 -> p3
//           -> gather16(r1) -> g16gemm2(r2) -> gather64 -> head(MFMA).

#define NN 100000
#define NE 1600000
#define SHIFT 8                      // 256 nodes per bucket
#define NB2 391                      // ceil(NN/256)
#define EPB 4096                     // edges per P1/P2 block
#define NBLK 391                     // ceil(NE/EPB)
#define CHUNK 7                      // ceil(NBLK/64) for colscan
#define BCAP 5120                    // LDS bucket capacity in p3 (mean 4096, sd 64)

typedef _Float16 half8 __attribute__((ext_vector_type(8)));
typedef float f32x4 __attribute__((ext_vector_type(4)));

__device__ __forceinline__ float rdl_f(float v, int l) {
    return __int_as_float(__builtin_amdgcn_readlane(__float_as_int(v), l));
}

// unpack one half2 word, accumulate into two fp32 lanes
__device__ __forceinline__ void h2acc(unsigned u, float& a, float& b) {
    __half2 h = *reinterpret_cast<__half2*>(&u);
    float2 f = __half22float2(h);
    a += f.x; b += f.y;
}
__device__ __forceinline__ unsigned packh2(float a, float b) {
    __half2 h = __floats2half2_rn(a, b);
    return *reinterpret_cast<unsigned*>(&h);
}
__device__ __forceinline__ unsigned sc2(unsigned u, float s) {
    __half2 h = *reinterpret_cast<__half2*>(&u);
    float2 f = __half22float2(h);
    return packh2(f.x * s, f.y * s);
}

// ---------------- P1: bucket counts (blocks < NBLK) + MFMA gemm1 (rest) ----------------
// gemm1_raw: A = x @ W1 (unscaled; dinv applied in P3), K=128, M=16, fp16 out.
__global__ __launch_bounds__(256) void count_gemm1_k(const int* __restrict__ dst,
                                                     int* __restrict__ mat,
                                                     const float* __restrict__ x,
                                                     const float* __restrict__ W1,
                                                     __half* __restrict__ A, int n) {
    __shared__ int cnt[NB2];
    __shared__ _Float16 sW1f[2048];          // 4 k-tiles x 64 lanes x 8 (frag layout)
    __shared__ unsigned sxu[4][16][68];      // per-wave fp16 x-tile, 136-half rows
    const int tid = threadIdx.x;
    if ((int)blockIdx.x < NBLK) {
        for (int i = tid; i < NB2; i += 256) cnt[i] = 0;
        __syncthreads();
        const int e0 = blockIdx.x * EPB;
        const int e1 = min(e0 + EPB, NE);
        int i = e0 + tid * 4;
        for (; i + 3 < e1; i += 1024) {
            const int4 d4 = *(const int4*)&dst[i];
            atomicAdd(&cnt[d4.x >> SHIFT], 1);
            atomicAdd(&cnt[d4.y >> SHIFT], 1);
            atomicAdd(&cnt[d4.z >> SHIFT], 1);
            atomicAdd(&cnt[d4.w >> SHIFT], 1);
        }
        for (; i < e1; ++i) atomicAdd(&cnt[dst[i] >> SHIFT], 1);
        __syncthreads();
        for (int c = tid; c < NB2; c += 256) mat[blockIdx.x * NB2 + c] = cnt[c];
        return;
    }
    const int bid = blockIdx.x - NBLK;
    const int row0 = bid * 64;
    for (int i = tid; i < 2048; i += 256) {
        const int kt = i >> 9;
        const int l = (i >> 3) & 63;
        const int j = i & 7;
        const int k = kt * 32 + ((l >> 4) << 3) + j;
        sW1f[i] = (_Float16)W1[k * 16 + (l & 15)];
    }
    const float4* in4 = (const float4*)x;
    for (int i = tid; i < 2048; i += 256) {
        const int r = i >> 5, kv = i & 31;
        const int g = row0 + r;
        float4 v = make_float4(0.f, 0.f, 0.f, 0.f);
        if (g < n) v = in4[(long)g * 32 + kv];
        unsigned* su = &sxu[r >> 4][r & 15][0];
        su[kv * 2]     = packh2(v.x, v.y);
        su[kv * 2 + 1] = packh2(v.z, v.w);
    }
    __syncthreads();
    const int w = tid >> 6, l = tid & 63;
    const int node0 = row0 + w * 16;
    f32x4 c = {0.f, 0.f, 0.f, 0.f};
#pragma unroll
    for (int kt = 0; kt < 4; ++kt) {
        const half8 a = *(const half8*)&sxu[w][l & 15][kt * 16 + ((l >> 4) << 2)];
        const half8 b = *(const half8*)&sW1f[kt * 512 + l * 8];
        c = __builtin_amdgcn_mfma_f32_16x16x32_f16(a, b, c, 0, 0, 0);
    }
#pragma unroll
    for (int i = 0; i < 4; ++i) {
        const int g = node0 + ((l >> 4) << 2) + i;
        if (g < n) A[(long)g * 16 + (l & 15)] = __float2half(c[i]);
    }
}

// ---------------- colscan: per-bucket exclusive scan over edge-blocks ----------------
__global__ __launch_bounds__(64) void colscan_k(const int* __restrict__ mat,
                                                int* __restrict__ ofsT,
                                                int* __restrict__ colTotal) {
    const int c = blockIdx.x;
    const int lane = threadIdx.x;
    int v[CHUNK];
    int s = 0;
    const int base = lane * CHUNK;
#pragma unroll
    for (int j = 0; j < CHUNK; ++j) {
        int b = base + j;
        int x_ = (b < NBLK) ? mat[b * NB2 + c] : 0;
        v[j] = s;              // local exclusive prefix
        s += x_;
    }
    int inc = s;
#pragma unroll
    for (int d = 1; d < 64; d <<= 1) {
        int t = __shfl_up(inc, d, 64);
        if (lane >= d) inc += t;
    }
    const int excl = inc - s;
#pragma unroll
    for (int j = 0; j < CHUNK; ++j) {
        int b = base + j;
        if (b < NBLK) ofsT[b * NB2 + c] = excl + v[j];
    }
    if (lane == 63) colTotal[c] = excl + s;
}

// ---------------- P2: scatter packed edges; block 0 publishes bucketBase -------------
// Wave-shuffle hybrid scan: 6 shfl_up steps + cross-wave LDS prefix, 1 barrier.
__global__ __launch_bounds__(512) void p2_scatter_k(const int* __restrict__ src,
                                                    const int* __restrict__ dst,
                                                    const int* __restrict__ ofsT,
                                                    const int* __restrict__ colTotal,
                                                    int* __restrict__ bucketBase,
                                                    unsigned* __restrict__ bucketed) {
    __shared__ int wsum[8];
    __shared__ int cur[NB2];
    const int b = blockIdx.x;
    const int t = threadIdx.x;
    const int lane = t & 63;
    const int w = t >> 6;
    const int v = (t < NB2) ? colTotal[t] : 0;
    int x = v;
#pragma unroll
    for (int d = 1; d < 64; d <<= 1) {
        const int y = __shfl_up(x, d, 64);
        if (lane >= d) x += y;
    }
    if (lane == 63) wsum[w] = x;
    __syncthreads();
    int add = 0;
#pragma unroll
    for (int i = 0; i < 7; ++i)
        if (i < w) add += wsum[i];
    const int incl = x + add;            // inclusive scan of colTotal over 512
    if (t < NB2) cur[t] = (incl - v) + ofsT[b * NB2 + t];
    if (b == 0) {
        if (t < NB2) bucketBase[t] = incl - v;
        if (t == NB2) bucketBase[NB2] = NE;
    }
    __syncthreads();
    const int e0 = b * EPB;
    const int e1 = min(e0 + EPB, NE);
    int i = e0 + t * 4;
    const int stride = 512 * 4;
    for (; i + 3 < e1; i += stride) {
        const int4 d4 = *(const int4*)&dst[i];
        const int4 s4 = *(const int4*)&src[i];
        const int p0 = atomicAdd(&cur[d4.x >> SHIFT], 1);
        const int p1 = atomicAdd(&cur[d4.y >> SHIFT], 1);
        const int p2 = atomicAdd(&cur[d4.z >> SHIFT], 1);
        const int p3 = atomicAdd(&cur[d4.w >> SHIFT], 1);
        bucketed[p0] = ((unsigned)s4.x << 8) | (unsigned)(d4.x & 255);
        bucketed[p1] = ((unsigned)s4.y << 8) | (unsigned)(d4.y & 255);
        bucketed[p2] = ((unsigned)s4.z << 8) | (unsigned)(d4.z & 255);
        bucketed[p3] = ((unsigned)s4.w << 8) | (unsigned)(d4.w & 255);
    }
    for (; i < e1; ++i) {
        const int d = dst[i];
        const int pos = atomicAdd(&cur[d >> SHIFT], 1);
        bucketed[pos] = ((unsigned)src[i] << 8) | (unsigned)(d & 255);
    }
}

// ---------------- P3: per-bucket CSR via LDS staging + A rescale ----------------
__global__ __launch_bounds__(512) void p3_csr_k(const unsigned* __restrict__ bucketed,
                                                const int* __restrict__ bucketBase,
                                                int* __restrict__ rowptr,
                                                float* __restrict__ dinv,
                                                int* __restrict__ csr_src,
                                                __half* __restrict__ A) {
    __shared__ unsigned sEdge[BCAP];
    __shared__ int sCsr[BCAP];
    __shared__ int cnt[256];
    __shared__ int excl[256];
    __shared__ float ld[256];
    const int c = blockIdx.x;
    const int t = threadIdx.x;
    const int base = bucketBase[c];
    const int end  = bucketBase[c + 1];
    const int sz = end - base;
    if (t < 256) cnt[t] = 0;
    const bool inLds = (sz <= BCAP);
    if (inLds) {
        for (int i = t; i < sz; i += 512) sEdge[i] = bucketed[base + i];
    }
    __syncthreads();
    // phase A: histogram
    if (inLds) {
        for (int i = t; i < sz; i += 512) atomicAdd(&cnt[sEdge[i] & 255u], 1);
    } else {
        for (int i = base + t; i < end; i += 512) atomicAdd(&cnt[bucketed[i] & 255u], 1);
    }
    __syncthreads();
    // phase B: inclusive scan of 256 counts (guarded for 512 threads)
    if (t < 256) excl[t] = cnt[t];
    __syncthreads();
    for (int off = 1; off < 256; off <<= 1) {
        int a = (t < 256 && t >= off) ? excl[t - off] : 0;
        __syncthreads();
        if (t < 256) excl[t] += a;
        __syncthreads();
    }
    const int node0 = c << SHIFT;
    if (t < 256) {
        const int node = node0 + t;
        const int ex = excl[t] - cnt[t];
        if (node < NN) {
            rowptr[node] = base + ex;
            const float dv = rsqrtf((float)cnt[t] + 1.0f);  // +1 self loop
            dinv[node] = dv;
            ld[t] = dv;
        }
        excl[t] = ex;  // becomes the fill cursor
    }
    if (c == NB2 - 1 && t == 0) rowptr[NN] = NE;
    __syncthreads();
    // phase C: scatter into csr window
    if (inLds) {
        for (int i = t; i < sz; i += 512) {
            const unsigned p = sEdge[i];
            const int pos = atomicAdd(&excl[p & 255u], 1);
            sCsr[pos] = (int)(p >> 8);
        }
        __syncthreads();
        for (int i = t; i < sz; i += 512) csr_src[base + i] = sCsr[i];
    } else {
        for (int i = base + t; i < end; i += 512) {
            const unsigned p = bucketed[i];
            const int pos = atomicAdd(&excl[p & 255u], 1);
            csr_src[base + pos] = (int)(p >> 8);
        }
    }
    // phase D: rescale A rows by dinv (2 threads per node)
    {
        const int node = node0 + (t >> 1);
        if (node < NN) {
            const float dv = ld[t >> 1];
            uint4* p = (uint4*)(A + (long)node * 16 + (t & 1) * 8);
            uint4 q = *p;
            q.x = sc2(q.x, dv); q.y = sc2(q.y, dv);
            q.z = sc2(q.z, dv); q.w = sc2(q.w, dv);
            *p = q;
        }
    }
}

// ---------------- pull-gather, 16 ch fp16 (persistent): B = dinv*relu(dg*(sum A)+b1) ----
__global__ __launch_bounds__(256) void gather16h_k(const int* __restrict__ rowptr,
                                                   const int* __restrict__ csr_src,
                                                   const float* __restrict__ dinv,
                                                   const __half* __restrict__ hs,
                                                   const float* __restrict__ bias,
                                                   __half* __restrict__ outp, int n) {
    const int lane = threadIdx.x & 63;
    const int wid0 = blockIdx.x * 4 + (threadIdx.x >> 6);
    const int nWaves = gridDim.x * 4;
    const int q = lane & 3;                 // uint2 chunk within 16-ch row
    const int sub = lane >> 2;              // edge subgroup 0..15
    const uint2* h2p = (const uint2*)hs;
    const float4 b = ((const float4*)bias)[q];
    for (int g = wid0; g < n; g += nWaves) {
        const float dg = dinv[g];
        const int beg = rowptr[g], end = rowptr[g + 1];
        float a0 = 0.f, a1 = 0.f, a2 = 0.f, a3 = 0.f;
        if (sub == 0) {                      // self term
            uint2 v = h2p[(long)g * 4 + q];
            h2acc(v.x, a0, a1); h2acc(v.y, a2, a3);
        }
        for (int j0 = beg; j0 < end; j0 += 16) {
            int idx = j0 + sub;
            if (idx < end) {
                const int s = csr_src[idx];
                uint2 v = h2p[(long)s * 4 + q];
                h2acc(v.x, a0, a1); h2acc(v.y, a2, a3);
            }
        }
#pragma unroll
        for (int m = 4; m <= 32; m <<= 1) {
            a0 += __shfl_xor(a0, m, 64);
            a1 += __shfl_xor(a1, m, 64);
            a2 += __shfl_xor(a2, m, 64);
            a3 += __shfl_xor(a3, m, 64);
        }
        if (sub == 0) {
            float v0 = fmaxf(fmaf(dg, a0, b.x), 0.0f) * dg;
            float v1 = fmaxf(fmaf(dg, a1, b.y), 0.0f) * dg;
            float v2 = fmaxf(fmaf(dg, a2, b.z), 0.0f) * dg;
            float v3 = fmaxf(fmaf(dg, a3, b.w), 0.0f) * dg;
            uint2 w;
            w.x = packh2(v0, v1);
            w.y = packh2(v2, v3);
            ((uint2*)outp)[(long)g * 4 + q] = w;
        }
    }
}

// ---------------- fused gather16 + gemm2: C = dinv*relu(dg*(sum B)@W2 + b2), fp16 out ----
__global__ __launch_bounds__(256) void g16gemm2h_k(const int* __restrict__ rowptr,
                                                   const int* __restrict__ csr_src,
                                                   const float* __restrict__ dinv,
                                                   const __half* __restrict__ hs,
                                                   const float* __restrict__ W2,
                                                   const float* __restrict__ b2,
                                                   __half* __restrict__ outp, int n) {
    const int lane = threadIdx.x & 63;
    const int wid = blockIdx.x * 4 + (threadIdx.x >> 6);
    const int nWaves = gridDim.x * 4;
    float w2[16];
#pragma unroll
    for (int k = 0; k < 16; ++k) w2[k] = W2[k * 64 + lane];
    const float bm = b2[lane];
    const int q = lane & 3;
    const int sub = lane >> 2;
    const uint2* h2p = (const uint2*)hs;
    for (int g = wid; g < n; g += nWaves) {
        const float dg = dinv[g];
        const int beg = rowptr[g], end = rowptr[g + 1];
        float a0 = 0.f, a1 = 0.f, a2 = 0.f, a3 = 0.f;
        if (sub == 0) {                      // self term
            uint2 v = h2p[(long)g * 4 + q];
            h2acc(v.x, a0, a1); h2acc(v.y, a2, a3);
        }
        for (int j0 = beg; j0 < end; j0 += 16) {
            int idx = j0 + sub;
            if (idx < end) {
                const int s = csr_src[idx];
                uint2 v = h2p[(long)s * 4 + q];
                h2acc(v.x, a0, a1); h2acc(v.y, a2, a3);
            }
        }
#pragma unroll
        for (int m = 4; m <= 32; m <<= 1) {
            a0 += __shfl_xor(a0, m, 64);
            a1 += __shfl_xor(a1, m, 64);
            a2 += __shfl_xor(a2, m, 64);
            a3 += __shfl_xor(a3, m, 64);
        }
        float t = 0.0f;
#pragma unroll
        for (int ql = 0; ql < 4; ++ql) {
            t = fmaf(rdl_f(a0, ql), w2[4 * ql + 0], t);
            t = fmaf(rdl_f(a1, ql), w2[4 * ql + 1], t);
            t = fmaf(rdl_f(a2, ql), w2[4 * ql + 2], t);
            t = fmaf(rdl_f(a3, ql), w2[4 * ql + 3], t);
        }
        float r = fmaxf(fmaf(dg, t, bm), 0.0f);   // dg*(sum)@W2 + b2, relu
        outp[(long)g * 64 + lane] = __float2half(r * dg);  // pre-scaled fp16
    }
}

// ---------------- pull-gather, 64 ch fp16 (R16 exact): agg = dg * sum C ----------------
__global__ __launch_bounds__(256) void gather64h_k(const int* __restrict__ rowptr,
                                                   const int* __restrict__ csr_src,
                                                   const float* __restrict__ dinv,
                                                   const __half* __restrict__ hs,
                                                   __half* __restrict__ outp, int n) {
    const int g = (blockIdx.x * 256 + threadIdx.x) >> 6;
    if (g >= n) return;
    const int lane = threadIdx.x & 63;
    const int q = lane & 7;                 // uint4 chunk within 64-ch row
    const int sub = lane >> 3;              // edge subgroup 0..7
    const float dg = dinv[g];
    const int beg = rowptr[g], end = rowptr[g + 1];
    const uint4* h4 = (const uint4*)hs;     // row = 8 chunks of 16B
    float a[8];
#pragma unroll
    for (int i = 0; i < 8; ++i) a[i] = 0.f;
    if (sub == 0) {                          // self term
        uint4 v = h4[(long)g * 8 + q];
        h2acc(v.x, a[0], a[1]); h2acc(v.y, a[2], a[3]);
        h2acc(v.z, a[4], a[5]); h2acc(v.w, a[6], a[7]);
    }
    int j0 = beg;
    for (; j0 + 16 <= end; j0 += 16) {
        const int s0 = csr_src[j0 + sub];
        const int s1 = csr_src[j0 + 8 + sub];
        const uint4 v0 = h4[(long)s0 * 8 + q];
        const uint4 v1 = h4[(long)s1 * 8 + q];
        h2acc(v0.x, a[0], a[1]); h2acc(v0.y, a[2], a[3]);
        h2acc(v0.z, a[4], a[5]); h2acc(v0.w, a[6], a[7]);
        h2acc(v1.x, a[0], a[1]); h2acc(v1.y, a[2], a[3]);
        h2acc(v1.z, a[4], a[5]); h2acc(v1.w, a[6], a[7]);
    }
    for (; j0 < end; j0 += 8) {
        int idx = j0 + sub;
        if (idx < end) {
            const int s = csr_src[idx];
            const uint4 v = h4[(long)s * 8 + q];
            h2acc(v.x, a[0], a[1]); h2acc(v.y, a[2], a[3]);
            h2acc(v.z, a[4], a[5]); h2acc(v.w, a[6], a[7]);
        }
    }
#pragma unroll
    for (int m = 8; m <= 32; m <<= 1) {
#pragma unroll
        for (int i = 0; i < 8; ++i) a[i] += __shfl_xor(a[i], m, 64);
    }
    if (sub == 0) {
        uint4 w;
        w.x = packh2(a[0] * dg, a[1] * dg);
        w.y = packh2(a[2] * dg, a[3] * dg);
        w.z = packh2(a[4] * dg, a[5] * dg);
        w.w = packh2(a[6] * dg, a[7] * dg);
        ((uint4*)outp)[(long)g * 8 + q] = w;
    }
}

// ---------------- MFMA head: out = relu(agg@W3 + b3).Wfc + bfc ----------------
__global__ __launch_bounds__(256) void head_mfma_k(const __half* __restrict__ agg,
                                                   const float* __restrict__ W3,
                                                   const float* __restrict__ b3,
                                                   const float* __restrict__ Wfc,
                                                   const float* __restrict__ bfc,
                                                   float* __restrict__ out, int n) {
    __shared__ _Float16 sWf[8192];           // 16 KB, frag-layout
    const int tid = threadIdx.x;
    for (int i = tid; i < 8192; i += 256) {
        const int j = i & 7;
        const int l = (i >> 3) & 63;
        const int th = i >> 9;
        const int k = (th & 1) * 32 + ((l >> 4) << 3) + j;
        const int nn = (th >> 1) * 16 + (l & 15);
        sWf[i] = (_Float16)W3[k * 128 + nn];
    }
    __syncthreads();
    const int lane = tid & 63;
    const int wid = blockIdx.x * 4 + (tid >> 6);
    const int nWaves = gridDim.x * 4;
    const int col = lane & 15;
    const int kg = lane >> 4;
    half8 wf[16];
#pragma unroll
    for (int q2 = 0; q2 < 16; ++q2)
        wf[q2] = *((const half8*)&sWf[(q2 * 64 + lane) * 8]);
    float b3v[8], wfv[8];
#pragma unroll
    for (int t = 0; t < 8; ++t) {
        b3v[t] = b3[t * 16 + col];
        wfv[t] = Wfc[t * 16 + col];
    }
    const float bb = bfc[0];
    const int nTiles = n >> 4;               // 6250, exact
    union { uint4 u; half8 h; } cva, cvb;
    for (int tile = wid; tile < nTiles; tile += nWaves) {
        const int node0 = tile << 4;
        const uint4* rowp = (const uint4*)(agg + (long)(node0 + col) * 64);
        cva.u = rowp[kg];                     // k = kg*8 .. +8   (half 0)
        cvb.u = rowp[4 + kg];                 // k = 32 + kg*8..  (half 1)
        const half8 a0 = cva.h, a1 = cvb.h;
        f32x4 c[8];
#pragma unroll
        for (int t = 0; t < 8; ++t) {
            f32x4 z = {0.f, 0.f, 0.f, 0.f};
            c[t] = __builtin_amdgcn_mfma_f32_16x16x32_f16(a0, wf[t * 2], z, 0, 0, 0);
            c[t] = __builtin_amdgcn_mfma_f32_16x16x32_f16(a1, wf[t * 2 + 1], c[t], 0, 0, 0);
        }
        float s0 = 0.f, s1 = 0.f, s2 = 0.f, s3 = 0.f;
#pragma unroll
        for (int t = 0; t < 8; ++t) {
            s0 += fmaxf(c[t][0] + b3v[t], 0.f) * wfv[t];
            s1 += fmaxf(c[t][1] + b3v[t], 0.f) * wfv[t];
            s2 += fmaxf(c[t][2] + b3v[t], 0.f) * wfv[t];
            s3 += fmaxf(c[t][3] + b3v[t], 0.f) * wfv[t];
        }
#pragma unroll
        for (int m = 1; m <= 8; m <<= 1) {
            s0 += __shfl_xor(s0, m, 64);
            s1 += __shfl_xor(s1, m, 64);
            s2 += __shfl_xor(s2, m, 64);
            s3 += __shfl_xor(s3, m, 64);
        }
        if (col == 0) {
            const int nb = node0 + kg * 4;
            out[nb]     = s0 + bb;
            out[nb + 1] = s1 + bb;
            out[nb + 2] = s2 + bb;
            out[nb + 3] = s3 + bb;
        }
    }
}

extern "C" void kernel_launch(void* const* d_in, const int* in_sizes, int n_in,
                              void* d_out, int out_size, void* d_ws, size_t ws_size,
                              hipStream_t stream) {
    const float* x    = (const float*)d_in[0];
    const int*   ei   = (const int*)d_in[1];       // [2,E]: src = ei, dst = ei+E
    const float* W1   = (const float*)d_in[2];
    const float* b1   = (const float*)d_in[3];
    const float* W2   = (const float*)d_in[4];
    const float* b2   = (const float*)d_in[5];
    const float* W3   = (const float*)d_in[6];
    const float* b3   = (const float*)d_in[7];
    const float* Wfc  = (const float*)d_in[8];
    const float* bfc  = (const float*)d_in[9];
    float* out = (float*)d_out;

    const int* src = ei;
    const int* dst = ei + NE;

    // workspace layout (16B-aligned offsets; 4B units):
    // dinv[N] | rowptr[N+8] | mat[NBLK*NB2] | ofsT[NBLK*NB2] | colTotal[512]
    // | bucketBase[512] | csr_src[E+64] | bucketed[E] u32
    // | A_h[16N] fp16 | B_h[16N] fp16 | C_h[64N] fp16 | agg_h[64N] fp16
    float* dinv        = (float*)d_ws;
    int*   rowptr      = (int*)(dinv + NN);
    int*   mat         = rowptr + NN + 8;
    int*   ofsT        = mat + NBLK * NB2 + 4;
    int*   colTotal    = ofsT + NBLK * NB2 + 4;
    int*   bucketBase  = colTotal + 512;
    int*   csr_src     = bucketBase + 512;
    unsigned* bucketed = (unsigned*)(csr_src + NE + 64);
    __half* A_h        = (__half*)(bucketed + NE);
    __half* B_h        = A_h + (long)NN * 16;
    __half* C_h        = B_h + (long)NN * 16;
    __half* agg_h      = C_h + (long)NN * 64;

    const int T = 256;

    // ---- CSR build (atomic-free) + MFMA gemm1 overlapped ----
    const int gemmBlocks = (NN + 63) / 64;             // 1563
    count_gemm1_k<<<NBLK + gemmBlocks, T, 0, stream>>>(dst, mat, x, W1, A_h, NN);
    colscan_k<<<NB2, 64, 0, stream>>>(mat, ofsT, colTotal);
    p2_scatter_k<<<NBLK, 512, 0, stream>>>(src, dst, ofsT, colTotal, bucketBase, bucketed);
    p3_csr_k<<<NB2, 512, 0, stream>>>(bucketed, bucketBase, rowptr, dinv, csr_src, A_h);

    // ---- B = dinv * relu(dg*(sum A) + b1)  (pre-scaled r1, 16ch fp16) ----
    gather16h_k<<<2048, T, 0, stream>>>(rowptr, csr_src, dinv, A_h, b1, B_h, NN);
    // ---- C = dinv * relu(dg*(sum B)@W2 + b2)  (pre-scaled r2, 64ch fp16) ----
    g16gemm2h_k<<<2048, T, 0, stream>>>(rowptr, csr_src, dinv, B_h, W2, b2, C_h, NN);
    // ---- agg(64ch fp16) = dg * sum C ----
    gather64h_k<<<(NN + 3) / 4, T, 0, stream>>>(rowptr, csr_src, dinv, C_h, agg_h, NN);
    // ---- head: out = relu(agg@W3 + b3).Wfc + bfc  (MFMA) ----
    head_mfma_k<<<256, T, 0, stream>>>(agg_h, W3, b3, Wfc, bfc, out, NN);
}